// Round 12
// baseline (404.992 us; speedup 1.0000x reference)
//
#include <hip/hip_runtime.h>
#include <hip/hip_bf16.h>
#include <math.h>

#define N_BUILD 200000
#define N_COMM  10000
#define E_BUILD 1200000
#define E_COMM  160000
#define NB_B 196   // scan blocks for building (200000/1024 rounded up)
#define NB_C 10
#define CHUNK 2048
#define CB_B ((E_BUILD + CHUNK - 1) / CHUNK)   // 586
#define CB_C ((E_COMM  + CHUNK - 1) / CHUNK)   // 79

typedef __bf16 bf16x8 __attribute__((ext_vector_type(8)));
typedef float  f32x4  __attribute__((ext_vector_type(4)));

// non-temporal loads: streaming data bypasses L2 residency so scatter dirty lines
// and reusable random rows keep the cache.
__device__ __forceinline__ int ntl_i(const int* p) { return __builtin_nontemporal_load(p); }
__device__ __forceinline__ int2 ntl_i2(const int2* p) {
    long long v = __builtin_nontemporal_load((const long long*)p);
    return __builtin_bit_cast(int2, v);
}

// ---------------- bf16 helpers (RNE) ----------------
__device__ __forceinline__ unsigned short f2b(float f) {
    unsigned int u = __builtin_bit_cast(unsigned int, f);
    u += 0x7fffu + ((u >> 16) & 1u);
    return (unsigned short)(u >> 16);
}
__device__ __forceinline__ float b2f(unsigned short h) {
    unsigned int u = ((unsigned int)h) << 16;
    return __builtin_bit_cast(float, u);
}
__device__ __forceinline__ unsigned int pk2(float a, float b) {
    return (unsigned int)f2b(a) | ((unsigned int)f2b(b) << 16);
}
__device__ __forceinline__ void up8(uint4 v, float* r) {
    r[0] = b2f((unsigned short)v.x); r[1] = b2f((unsigned short)(v.x >> 16));
    r[2] = b2f((unsigned short)v.y); r[3] = b2f((unsigned short)(v.y >> 16));
    r[4] = b2f((unsigned short)v.z); r[5] = b2f((unsigned short)(v.z >> 16));
    r[6] = b2f((unsigned short)v.w); r[7] = b2f((unsigned short)(v.w >> 16));
}

// ---------------- merged init: zero counts + out prefill + all weight prep ----------------
#define INIT_TOT (N_BUILD + N_COMM + 2 * N_BUILD + N_COMM * 32 + 2048 + 4096 + 16384 + 8192)
__global__ __launch_bounds__(256) void init_k(int* cnt_b, int* cnt_c, float* out,
                                              const float* __restrict__ cF, unsigned short* __restrict__ cFb,
                                              const float* __restrict__ W_c1, unsigned short* __restrict__ Wt_c1,
                                              const float* __restrict__ W_c2, unsigned short* __restrict__ Wt_c2,
                                              const float* __restrict__ W_b1, unsigned short* __restrict__ Wt_b1,
                                              const float* __restrict__ W_b2, unsigned short* __restrict__ Wt_b2) {
    int i = blockIdx.x * blockDim.x + threadIdx.x;
    if (i < N_BUILD) { cnt_b[i] = 0; return; }
    i -= N_BUILD;
    if (i < N_COMM) { cnt_c[i] = 0; return; }
    i -= N_COMM;
    if (i < 2 * N_BUILD) { out[i] = -0.69314718056f; return; }
    i -= 2 * N_BUILD;
    if (i < N_COMM * 32) { cFb[i] = f2b(cF[i]); return; }
    i -= N_COMM * 32;
    if (i < 2048) { Wt_c1[(i % 64) * 32 + i / 64] = f2b(W_c1[i]); return; }
    i -= 2048;
    if (i < 4096) { Wt_c2[(i % 64) * 64 + i / 64] = f2b(W_c2[i]); return; }
    i -= 4096;
    if (i < 16384) { Wt_b1[(i % 128) * 128 + i / 128] = f2b(W_b1[i]); return; }
    i -= 16384;
    if (i < 8192) { Wt_b2[(i % 64) * 128 + i / 64] = f2b(W_b2[i]); }
}

// ---------------- merged CSR build kernels ----------------

__global__ __launch_bounds__(256) void hist2_k(int* cnt_b, const int* __restrict__ b_dst,
                                               int* cnt_c, const int* __restrict__ c_dst) {
    int i = blockIdx.x * blockDim.x + threadIdx.x;
    if (i < E_BUILD) atomicAdd(&cnt_b[ntl_i(&b_dst[i])], 1);
    else if (i < E_BUILD + E_COMM) atomicAdd(&cnt_c[ntl_i(&c_dst[i - E_BUILD])], 1);
}

__global__ __launch_bounds__(256) void scan1m_k(const int* __restrict__ cnt_b, int* __restrict__ ex_b, int* __restrict__ bs_b,
                                                const int* __restrict__ cnt_c, int* __restrict__ ex_c, int* __restrict__ bs_c) {
    __shared__ int sdata[256];
    const int tid = threadIdx.x;
    const int* cnt; int* ex; int* bs; int n, blk;
    if ((int)blockIdx.x < NB_B) { cnt = cnt_b; ex = ex_b; bs = bs_b; n = N_BUILD; blk = blockIdx.x; }
    else                        { cnt = cnt_c; ex = ex_c; bs = bs_c; n = N_COMM;  blk = blockIdx.x - NB_B; }
    const int base = blk * 1024 + tid * 4;
    int v[4]; int s = 0;
#pragma unroll
    for (int j = 0; j < 4; ++j) { v[j] = (base + j < n) ? cnt[base + j] : 0; s += v[j]; }
    sdata[tid] = s; __syncthreads();
    for (int off = 1; off < 256; off <<= 1) {
        int t = (tid >= off) ? sdata[tid - off] : 0;
        __syncthreads();
        sdata[tid] += t;
        __syncthreads();
    }
    if (tid == 255) bs[blk] = sdata[255];
    int run = sdata[tid] - s;
#pragma unroll
    for (int j = 0; j < 4; ++j) { if (base + j < n) ex[base + j] = run; run += v[j]; }
}

__global__ __launch_bounds__(256) void scan2m_k(int* bs_b, int* bs_c) {
    __shared__ int sdata[256];
    int* bs = (blockIdx.x == 0) ? bs_b : bs_c;
    int nb  = (blockIdx.x == 0) ? NB_B : NB_C;
    const int tid = threadIdx.x;
    int v = (tid < nb) ? bs[tid] : 0;
    sdata[tid] = v; __syncthreads();
    for (int off = 1; off < 256; off <<= 1) {
        int t = (tid >= off) ? sdata[tid - off] : 0;
        __syncthreads();
        sdata[tid] += t;
        __syncthreads();
    }
    if (tid < nb) bs[tid] = sdata[tid] - v;
}

__global__ __launch_bounds__(256) void finalizem_k(const int* __restrict__ cnt_b, int* rp_b, const int* __restrict__ bo_b,
                                                   int* cur_b, float* di_b,
                                                   const int* __restrict__ cnt_c, int* rp_c, const int* __restrict__ bo_c,
                                                   int* cur_c, float* di_c) {
    int i = blockIdx.x * blockDim.x + threadIdx.x;
    if (i < N_BUILD) {
        int cc = cnt_b[i];
        int r = rp_b[i] + bo_b[i >> 10];
        rp_b[i] = r; cur_b[i] = r; di_b[i] = 1.0f / (float)(cc + 1);
        if (i == 0) { rp_b[N_BUILD] = E_BUILD; rp_c[N_COMM] = E_COMM; }
    } else if (i < N_BUILD + N_COMM) {
        int ic = i - N_BUILD;
        int cc = cnt_c[ic];
        int r = rp_c[ic] + bo_c[ic >> 10];
        rp_c[ic] = r; cur_c[ic] = r; di_c[ic] = 1.0f / (float)(cc + 1);
    }
}

// XCD-range-partitioned community CSR scatter (int2: src, w)
__global__ __launch_bounds__(256) void csr_scatterc_k(const int* __restrict__ c_src, const int* __restrict__ c_dst,
                                                      int* cur_c, const float* __restrict__ di_c, int2* __restrict__ cse_c) {
    const int cid = blockIdx.x >> 3, x = blockIdx.x & 7;
    constexpr int NDIV = N_COMM / 8;
    int base = cid * CHUNK + threadIdx.x;
#pragma unroll
    for (int j = 0; j < CHUNK / 256; ++j, base += 256) {
        if (base < E_COMM) {
            int d = ntl_i(&c_dst[base]);
            if ((unsigned)d / (unsigned)NDIV == (unsigned)x) {
                int s = ntl_i(&c_src[base]);
                int pos = atomicAdd(&cur_c[d], 1);
                cse_c[pos] = make_int2(s, __float_as_int(sqrtf(di_c[s] * di_c[d])));
            }
        }
    }
}

// Building CSR scatter (after attscal): emits cse_b=(src,w) for layers 2/3 and
// exb=(w*a1(src), mbl(src)) for layer-1 aggregation. NT edge streams keep the
// dirty cse/exb lines + nmeta resident in each XCD's L2.
__global__ __launch_bounds__(256) void csr_scatterb_k(const int* __restrict__ b_src, const int* __restrict__ b_dst,
                                                      int* cur_b, const float* __restrict__ di_b,
                                                      const int4* __restrict__ nmeta,
                                                      int2* __restrict__ cse_b, int2* __restrict__ exb) {
    const int cid = blockIdx.x >> 3, x = blockIdx.x & 7;
    constexpr int NDIV = N_BUILD / 8;
    int base = cid * CHUNK + threadIdx.x;
#pragma unroll
    for (int j = 0; j < CHUNK / 256; ++j, base += 256) {
        if (base < E_BUILD) {
            int d = ntl_i(&b_dst[base]);
            if ((unsigned)d / (unsigned)NDIV == (unsigned)x) {
                int s = ntl_i(&b_src[base]);
                int pos = atomicAdd(&cur_b[d], 1);
                int4 nm = nmeta[s];
                float w = sqrtf(__int_as_float(nm.x) * di_b[d]);
                cse_b[pos] = make_int2(s, __float_as_int(w));
                exb[pos]   = make_int2(__float_as_int(w * __int_as_float(nm.y)), nm.z);
            }
        }
    }
}

// ---------------- MFMA GEMM: H[M][N] (bf16) = X[M][K] (bf16) @ Wt[N][K]^T ----------------
template<int K, int N, bool GUARD>
__global__ __launch_bounds__(256) void gemm_mfma_k(const unsigned short* __restrict__ X,
                                                   const unsigned short* __restrict__ Wt,
                                                   unsigned short* __restrict__ H, int M) {
    constexpr int GPR = K / 8;
    __shared__ unsigned short sA[64 * K];
    __shared__ unsigned short sB[N * K];
    const int tid  = threadIdx.x;
    const int row0 = blockIdx.x * 64;

    for (int idx = tid; idx < 64 * GPR; idx += 256) {
        int r = idx / GPR, g = idx % GPR;
        uint4 v = make_uint4(0u, 0u, 0u, 0u);
        if (!GUARD || row0 + r < M)
            v = *(const uint4*)&X[(size_t)(row0 + r) * K + g * 8];
        int gs = g ^ (r & (GPR - 1));
        *(uint4*)&sA[r * K + gs * 8] = v;
    }
    for (int idx = tid; idx < N * GPR; idx += 256) {
        int r = idx / GPR, g = idx % GPR;
        uint4 v = *(const uint4*)&Wt[(size_t)r * K + g * 8];
        int gs = g ^ (r & (GPR - 1));
        *(uint4*)&sB[r * K + gs * 8] = v;
    }
    __syncthreads();

    const int wave = tid >> 6, lane = tid & 63;
    const int rA = wave * 16 + (lane & 15);
    const int kg = lane >> 4;

    f32x4 zero = {0.f, 0.f, 0.f, 0.f};
    f32x4 acc[N / 16];
#pragma unroll
    for (int t = 0; t < N / 16; ++t) acc[t] = zero;

#pragma unroll
    for (int ks = 0; ks < K / 32; ++ks) {
        int gA = (ks * 4 + kg) ^ (rA & (GPR - 1));
        bf16x8 a = *(const bf16x8*)&sA[rA * K + gA * 8];
#pragma unroll
        for (int t = 0; t < N / 16; ++t) {
            int rB = t * 16 + (lane & 15);
            int gB = (ks * 4 + kg) ^ (rB & (GPR - 1));
            bf16x8 b = *(const bf16x8*)&sB[rB * K + gB * 8];
            acc[t] = __builtin_amdgcn_mfma_f32_16x16x32_bf16(a, b, acc[t], 0, 0, 0);
        }
    }

    const int crow = wave * 16 + (lane >> 4) * 4;
    const int ccol = lane & 15;
#pragma unroll
    for (int t = 0; t < N / 16; ++t) {
#pragma unroll
        for (int j = 0; j < 4; ++j) {
            int r = row0 + crow + j;
            if (!GUARD || r < M)
                H[(size_t)r * N + t * 16 + ccol] = f2b(acc[t][j]);
        }
    }
}

// ---------------- attention scalars ----------------
// Per local building i (g = l2g[i]): a = softmax([bF,bc]@Watt + batt);
// writes bFl[i] = a0*bf16(bF[g]) (PRE-SCALED) and nmeta[i] = (dinv, a1, map[g]).
__global__ __launch_bounds__(256) void attscal_k(const float* __restrict__ bF,
                                                 const unsigned short* __restrict__ cx,
                                                 const int* __restrict__ map,
                                                 const int* __restrict__ l2g,
                                                 const float* __restrict__ Watt,  // [128][2]
                                                 const float* __restrict__ batt,  // [2]
                                                 const float* __restrict__ dinv,
                                                 unsigned short* __restrict__ bFl,
                                                 int4* __restrict__ nmeta, int n) {
    __shared__ float sW0[128], sW1[128];
    if (threadIdx.x < 128) {
        sW0[threadIdx.x] = Watt[threadIdx.x * 2 + 0];
        sW1[threadIdx.x] = Watt[threadIdx.x * 2 + 1];
    }
    __syncthreads();
    int gid = blockIdx.x * blockDim.x + threadIdx.x;
    int i = gid >> 3, j = gid & 7;
    if (i >= n) return;
    int g = l2g[i];
    int mg = map[g];
    const float* f1 = &bF[(size_t)g * 64 + j * 8];
    const unsigned short* f2 = &cx[(size_t)mg * 64 + j * 8];
    float r1[8], r2[8];
    {
        float4 v0 = *(const float4*)&f1[0];
        float4 v1 = *(const float4*)&f1[4];
        r1[0]=v0.x; r1[1]=v0.y; r1[2]=v0.z; r1[3]=v0.w;
        r1[4]=v1.x; r1[5]=v1.y; r1[6]=v1.z; r1[7]=v1.w;
        uint4 u = *(const uint4*)&f2[0];
        up8(u, r2);
    }
    float l0 = 0.f, l1 = 0.f;
#pragma unroll
    for (int k = 0; k < 8; ++k) {
        l0 = fmaf(r1[k], sW0[j * 8 + k], l0);
        l1 = fmaf(r1[k], sW1[j * 8 + k], l1);
        l0 = fmaf(r2[k], sW0[64 + j * 8 + k], l0);
        l1 = fmaf(r2[k], sW1[64 + j * 8 + k], l1);
    }
#pragma unroll
    for (int m = 1; m < 8; m <<= 1) {
        l0 += __shfl_xor(l0, m, 8);
        l1 += __shfl_xor(l1, m, 8);
    }
    l0 += batt[0]; l1 += batt[1];
    float mm = fmaxf(l0, l1);
    float e0 = __expf(l0 - mm), e1 = __expf(l1 - mm);
    float inv = 1.0f / (e0 + e1);
    float a0 = e0 * inv, a1 = e1 * inv;
    uint4 o;
    o.x = pk2(r1[0]*a0, r1[1]*a0); o.y = pk2(r1[2]*a0, r1[3]*a0);
    o.z = pk2(r1[4]*a0, r1[5]*a0); o.w = pk2(r1[6]*a0, r1[7]*a0);
    *(uint4*)&bFl[(size_t)i * 64 + j * 8] = o;
    if (j == 0)
        nmeta[i] = make_int4(__float_as_int(dinv[i]), __float_as_int(a1), mg, 0);
}

// ---------------- layer-1 aggregation over FUSED features (pre-GEMM, linearity) ----------------
// y1[i][0:64]   = sum_e w_e * bFl[s]            (bFl pre-scaled by a0)   + dinv*bFl[i]
// y1[i][64:128] = sum_e (w_e*a1(s)) * cx2[mbl(s)]                        + dinv*a1(i)*cx2[mbl(i)]
// Lower lanes stream cse_b=(src,w); upper lanes stream exb=(wa1,mbl). NT streams
// keep bFl/cx2 random rows cached.
__global__ __launch_bounds__(256) void agg1_k(const int* __restrict__ rowptr,
                                              const int2* __restrict__ cse,
                                              const int2* __restrict__ exb,
                                              const unsigned short* __restrict__ bFl,   // [N][64]
                                              const unsigned short* __restrict__ cx2,   // [N_COMM][64]
                                              const int4* __restrict__ nmeta,
                                              unsigned short* __restrict__ y1,          // [N][128]
                                              int nGrp) {
    int wid = (blockIdx.x * blockDim.x + threadIdx.x) >> 6;
    int lane = threadIdx.x & 63;
    if (wid >= nGrp) return;
    int node = wid * 4 + (lane >> 4);
    int sl = lane & 15;
    bool upper = sl >= 8;
    int c = (sl & 7) * 8;
    int beg = rowptr[node], end = rowptr[node + 1];
    // self term
    int4 nm = nmeta[node];
    float di = __int_as_float(nm.x);
    uint4 hv = upper ? *(const uint4*)&cx2[(size_t)nm.z * 64 + c]
                     : *(const uint4*)&bFl[(size_t)node * 64 + c];
    float selfw = upper ? di * __int_as_float(nm.y) : di;
    const int2* es = upper ? exb : cse;
    float acc[8];
#pragma unroll
    for (int i = 0; i < 8; ++i) acc[i] = 0.f;
    for (int p = beg; p < end; p += 8) {
        int2 q[8];
#pragma unroll
        for (int t = 0; t < 8; ++t) { int e = p + t; q[t] = ntl_i2(&es[e < end ? e : 0]); }
        uint4 v[8];
#pragma unroll
        for (int t = 0; t < 8; ++t) {
            const unsigned short* base = upper ? &cx2[(size_t)q[t].y * 64 + c]
                                               : &bFl[(size_t)q[t].x * 64 + c];
            v[t] = *(const uint4*)base;
        }
#pragma unroll
        for (int t = 0; t < 8; ++t) {
            float sc = __int_as_float(upper ? q[t].x : q[t].y);
            float w = (p + t < end) ? sc : 0.f;
            float r[8]; up8(v[t], r);
#pragma unroll
            for (int i = 0; i < 8; ++i) acc[i] = fmaf(r[i], w, acc[i]);
        }
    }
    float hr[8]; up8(hv, hr);
#pragma unroll
    for (int i = 0; i < 8; ++i) acc[i] = fmaf(hr[i], selfw, acc[i]);
    uint4 ov;
    ov.x = pk2(acc[0], acc[1]); ov.y = pk2(acc[2], acc[3]);
    ov.z = pk2(acc[4], acc[5]); ov.w = pk2(acc[6], acc[7]);
    *(uint4*)&y1[(size_t)node * 128 + sl * 8] = ov;
}

// ---------------- double GEMM: h2 = relu(y1@W1 + b1) @ W2 ----------------
__global__ __launch_bounds__(256) void gemm2x_k(const unsigned short* __restrict__ y1,
                                                const unsigned short* __restrict__ Wt1,  // [128][128]
                                                const float* __restrict__ b1,            // [128]
                                                const unsigned short* __restrict__ Wt2,  // [64][128]
                                                unsigned short* __restrict__ H) {        // [N][64]
    constexpr int K = 128, GPR = 16;
    __shared__ unsigned short sA[64 * K];
    __shared__ unsigned short sB1[128 * K];
    __shared__ unsigned short sB2[64 * K];
    const int tid = threadIdx.x;
    const int row0 = blockIdx.x * 64;
    for (int idx = tid; idx < 64 * GPR; idx += 256) {
        int r = idx / GPR, g = idx % GPR;
        uint4 v = *(const uint4*)&y1[(size_t)(row0 + r) * K + g * 8];
        int gs = g ^ (r & (GPR - 1));
        *(uint4*)&sA[r * K + gs * 8] = v;
    }
    for (int idx = tid; idx < 128 * GPR; idx += 256) {
        int r = idx / GPR, g = idx % GPR;
        uint4 v = *(const uint4*)&Wt1[(size_t)r * K + g * 8];
        int gs = g ^ (r & (GPR - 1));
        *(uint4*)&sB1[r * K + gs * 8] = v;
    }
    for (int idx = tid; idx < 64 * GPR; idx += 256) {
        int r = idx / GPR, g = idx % GPR;
        uint4 v = *(const uint4*)&Wt2[(size_t)r * K + g * 8];
        int gs = g ^ (r & (GPR - 1));
        *(uint4*)&sB2[r * K + gs * 8] = v;
    }
    __syncthreads();
    const int wave = tid >> 6, lane = tid & 63;
    const int rA = wave * 16 + (lane & 15);
    const int kg = lane >> 4;
    const int crow = wave * 16 + (lane >> 4) * 4;
    const int ccol = lane & 15;
    f32x4 zero = {0.f, 0.f, 0.f, 0.f};
    f32x4 acc1[8];
#pragma unroll
    for (int t = 0; t < 8; ++t) acc1[t] = zero;
#pragma unroll
    for (int ks = 0; ks < 4; ++ks) {
        int gA = (ks * 4 + kg) ^ (rA & (GPR - 1));
        bf16x8 a = *(const bf16x8*)&sA[rA * K + gA * 8];
#pragma unroll
        for (int t = 0; t < 8; ++t) {
            int rB = t * 16 + (lane & 15);
            int gB = (ks * 4 + kg) ^ (rB & (GPR - 1));
            bf16x8 b = *(const bf16x8*)&sB1[rB * K + gB * 8];
            acc1[t] = __builtin_amdgcn_mfma_f32_16x16x32_bf16(a, b, acc1[t], 0, 0, 0);
        }
    }
    __syncthreads();
#pragma unroll
    for (int t = 0; t < 8; ++t) {
        float bv = b1[t * 16 + ccol];
#pragma unroll
        for (int j = 0; j < 4; ++j) {
            float x = fmaxf(acc1[t][j] + bv, 0.f);
            int r = crow + j;
            int ch = t * 16 + ccol;
            sA[r * K + (((ch >> 3) ^ (r & (GPR - 1))) << 3) + (ch & 7)] = f2b(x);
        }
    }
    __syncthreads();
    f32x4 acc2[4];
#pragma unroll
    for (int t = 0; t < 4; ++t) acc2[t] = zero;
#pragma unroll
    for (int ks = 0; ks < 4; ++ks) {
        int gA = (ks * 4 + kg) ^ (rA & (GPR - 1));
        bf16x8 a = *(const bf16x8*)&sA[rA * K + gA * 8];
#pragma unroll
        for (int t = 0; t < 4; ++t) {
            int rB = t * 16 + (lane & 15);
            int gB = (ks * 4 + kg) ^ (rB & (GPR - 1));
            bf16x8 b = *(const bf16x8*)&sB2[rB * K + gB * 8];
            acc2[t] = __builtin_amdgcn_mfma_f32_16x16x32_bf16(a, b, acc2[t], 0, 0, 0);
        }
    }
#pragma unroll
    for (int t = 0; t < 4; ++t)
#pragma unroll
        for (int jj = 0; jj < 4; ++jj)
            H[(size_t)(row0 + crow + jj) * 64 + t * 16 + ccol] = f2b(acc2[t][jj]);
}

// ---------------- gathers: deep lane-split node packing ----------------
template<int F, bool RELU>
__global__ __launch_bounds__(256) void gatherF_k(const int* __restrict__ rowptr,
                                                 const int2* __restrict__ cse,
                                                 const unsigned short* __restrict__ h,
                                                 const float* __restrict__ dinv,
                                                 const float* __restrict__ bias,
                                                 unsigned short* __restrict__ out, int nGrp) {
    constexpr int LPN = F / 8;
    constexpr int NPW = 64 / LPN;
    int wid = (blockIdx.x * blockDim.x + threadIdx.x) >> 6;
    int lane = threadIdx.x & 63;
    if (wid >= nGrp) return;
    int node = wid * NPW + lane / LPN;
    int c = (lane % LPN) * 8;
    int beg = rowptr[node], end = rowptr[node + 1];
    uint4 hv = *(const uint4*)&h[(size_t)node * F + c];
    float iv = dinv[node];
    float4 bb0 = *(const float4*)&bias[c];
    float4 bb1 = *(const float4*)&bias[c + 4];
    float acc[8];
#pragma unroll
    for (int i = 0; i < 8; ++i) acc[i] = 0.f;
    for (int p = beg; p < end; p += 8) {
        int2 q[8]; uint4 v[8];
#pragma unroll
        for (int t = 0; t < 8; ++t) { int e = p + t; q[t] = ntl_i2(&cse[e < end ? e : 0]); }
#pragma unroll
        for (int t = 0; t < 8; ++t) v[t] = *(const uint4*)&h[(size_t)q[t].x * F + c];
#pragma unroll
        for (int t = 0; t < 8; ++t) {
            float w = (p + t < end) ? __int_as_float(q[t].y) : 0.f;
            float r[8]; up8(v[t], r);
#pragma unroll
            for (int i = 0; i < 8; ++i) acc[i] = fmaf(r[i], w, acc[i]);
        }
    }
    float hr[8]; up8(hv, hr);
    float o[8];
    o[0] = fmaf(hr[0], iv, acc[0]) + bb0.x; o[1] = fmaf(hr[1], iv, acc[1]) + bb0.y;
    o[2] = fmaf(hr[2], iv, acc[2]) + bb0.z; o[3] = fmaf(hr[3], iv, acc[3]) + bb0.w;
    o[4] = fmaf(hr[4], iv, acc[4]) + bb1.x; o[5] = fmaf(hr[5], iv, acc[5]) + bb1.y;
    o[6] = fmaf(hr[6], iv, acc[6]) + bb1.z; o[7] = fmaf(hr[7], iv, acc[7]) + bb1.w;
    if (RELU) {
#pragma unroll
        for (int i = 0; i < 8; ++i) o[i] = fmaxf(o[i], 0.f);
    }
    uint4 ov;
    ov.x = pk2(o[0], o[1]); ov.y = pk2(o[2], o[3]);
    ov.z = pk2(o[4], o[5]); ov.w = pk2(o[6], o[7]);
    *(uint4*)&out[(size_t)node * F + c] = ov;
}

// building layer-2 gather fused with layer-3 XW (64 -> 2): 8 nodes/wave, 8 lanes/node.
__global__ __launch_bounds__(256) void gather64_dot_k(const int* __restrict__ rowptr,
                                                      const int2* __restrict__ cse,
                                                      const unsigned short* __restrict__ h,
                                                      const float* __restrict__ dinv,
                                                      const float* __restrict__ bias,
                                                      const float* __restrict__ W3,  // [64][2]
                                                      float* __restrict__ Dh, int nOct) {
    int wid = (blockIdx.x * blockDim.x + threadIdx.x) >> 6;
    int lane = threadIdx.x & 63;
    if (wid >= nOct) return;
    int node = wid * 8 + (lane >> 3);
    int sl = lane & 7, c = sl * 8;
    int beg = rowptr[node], end = rowptr[node + 1];
    uint4 hv = *(const uint4*)&h[(size_t)node * 64 + c];
    float iv = dinv[node];
    float4 bb0 = *(const float4*)&bias[c];
    float4 bb1 = *(const float4*)&bias[c + 4];
    float4 w4[4];
#pragma unroll
    for (int i = 0; i < 4; ++i) w4[i] = *(const float4*)&W3[c * 2 + i * 4];
    float acc[8];
#pragma unroll
    for (int i = 0; i < 8; ++i) acc[i] = 0.f;
    for (int p = beg; p < end; p += 8) {
        int2 q[8]; uint4 v[8];
#pragma unroll
        for (int t = 0; t < 8; ++t) { int e = p + t; q[t] = ntl_i2(&cse[e < end ? e : 0]); }
#pragma unroll
        for (int t = 0; t < 8; ++t) v[t] = *(const uint4*)&h[(size_t)q[t].x * 64 + c];
#pragma unroll
        for (int t = 0; t < 8; ++t) {
            float w = (p + t < end) ? __int_as_float(q[t].y) : 0.f;
            float r[8]; up8(v[t], r);
#pragma unroll
            for (int i = 0; i < 8; ++i) acc[i] = fmaf(r[i], w, acc[i]);
        }
    }
    float hr[8]; up8(hv, hr);
    float o[8];
    o[0] = fmaf(hr[0], iv, acc[0]) + bb0.x; o[1] = fmaf(hr[1], iv, acc[1]) + bb0.y;
    o[2] = fmaf(hr[2], iv, acc[2]) + bb0.z; o[3] = fmaf(hr[3], iv, acc[3]) + bb0.w;
    o[4] = fmaf(hr[4], iv, acc[4]) + bb1.x; o[5] = fmaf(hr[5], iv, acc[5]) + bb1.y;
    o[6] = fmaf(hr[6], iv, acc[6]) + bb1.z; o[7] = fmaf(hr[7], iv, acc[7]) + bb1.w;
#pragma unroll
    for (int i = 0; i < 8; ++i) o[i] = fmaxf(o[i], 0.f);
    float d0 = 0.f, d1 = 0.f;
#pragma unroll
    for (int i = 0; i < 4; ++i) {
        d0 = fmaf(o[2*i],   w4[i].x, d0); d0 = fmaf(o[2*i+1], w4[i].z, d0);
        d1 = fmaf(o[2*i],   w4[i].y, d1); d1 = fmaf(o[2*i+1], w4[i].w, d1);
    }
#pragma unroll
    for (int m = 1; m < 8; m <<= 1) {
        d0 += __shfl_xor(d0, m, 8);
        d1 += __shfl_xor(d1, m, 8);
    }
    if (sl == 0) {
        Dh[2 * (size_t)node + 0] = d0;
        Dh[2 * (size_t)node + 1] = d1;
    }
}

// final layer: gather (F=2, f32) + bias + log-softmax + scatter to global order
__global__ __launch_bounds__(256) void gather2_logsm_k(const int* __restrict__ rowptr,
                                                       const int2* __restrict__ cse,
                                                       const float* __restrict__ h2,
                                                       const float* __restrict__ dinv,
                                                       const float* __restrict__ bias,
                                                       const int* __restrict__ l2g,
                                                       float* __restrict__ out, int n) {
    int i = blockIdx.x * blockDim.x + threadIdx.x;
    if (i >= n) return;
    int beg = rowptr[i], end = rowptr[i + 1];
    float2 hv = *(const float2*)&h2[2 * (size_t)i];
    float iv = dinv[i];
    float a = 0.f, b = 0.f;
    for (int p = beg; p < end; p += 8) {
        int2 q[8]; float2 v[8];
#pragma unroll
        for (int t = 0; t < 8; ++t) { int e = p + t; q[t] = ntl_i2(&cse[e < end ? e : 0]); }
#pragma unroll
        for (int t = 0; t < 8; ++t) v[t] = *(const float2*)&h2[2 * (size_t)q[t].x];
#pragma unroll
        for (int t = 0; t < 8; ++t) {
            float w = (p + t < end) ? __int_as_float(q[t].y) : 0.f;
            a = fmaf(v[t].x, w, a);
            b = fmaf(v[t].y, w, b);
        }
    }
    a = fmaf(hv.x, iv, a) + bias[0];
    b = fmaf(hv.y, iv, b) + bias[1];
    float m = fmaxf(a, b);
    float ls = m + logf(__expf(a - m) + __expf(b - m));
    int g = l2g[i];
    out[2 * (size_t)g + 0] = a - ls;
    out[2 * (size_t)g + 1] = b - ls;
}

// ---------------- launch ----------------

static inline dim3 g1(long long n, int tpb = 256) { return dim3((unsigned)((n + tpb - 1) / tpb)); }

extern "C" void kernel_launch(void* const* d_in, const int* in_sizes, int n_in,
                              void* d_out, int out_size, void* d_ws, size_t ws_size,
                              hipStream_t stream) {
    const float* bF   = (const float*)d_in[0];
    const float* cF   = (const float*)d_in[1];
    const float* W_c1 = (const float*)d_in[2];
    const float* b_c1 = (const float*)d_in[3];
    const float* W_c2 = (const float*)d_in[4];
    const float* b_c2 = (const float*)d_in[5];
    const float* W_at = (const float*)d_in[6];
    const float* b_at = (const float*)d_in[7];
    const float* W_b1 = (const float*)d_in[8];
    const float* b_b1 = (const float*)d_in[9];
    const float* W_b2 = (const float*)d_in[10];
    const float* b_b2 = (const float*)d_in[11];
    const float* W_b3 = (const float*)d_in[12];
    const float* b_b3 = (const float*)d_in[13];
    const int* b_src = (const int*)d_in[14];
    const int* b_dst = (const int*)d_in[15];
    const int* c_src = (const int*)d_in[16];
    const int* c_dst = (const int*)d_in[17];
    const int* map   = (const int*)d_in[18];
    const int* l2g   = (const int*)d_in[19];
    float* out = (float*)d_out;

    char* p = (char*)d_ws;
    auto alloc = [&](size_t bytes) { char* q = p; p += (bytes + 15) & ~(size_t)15; return q; };
    int*   cnt_b    = (int*)  alloc(N_BUILD * 4);
    int*   rowptr_b = (int*)  alloc((N_BUILD + 4) * 4);
    int*   cursor_b = (int*)  alloc(N_BUILD * 4);
    int*   bsum_b   = (int*)  alloc(256 * 4);
    int*   cnt_c    = (int*)  alloc(N_COMM * 4);
    int*   rowptr_c = (int*)  alloc((N_COMM + 4) * 4);
    int*   cursor_c = (int*)  alloc(N_COMM * 4);
    int*   bsum_c   = (int*)  alloc(256 * 4);
    int2*  cse_b    = (int2*) alloc((size_t)E_BUILD * 8);
    int2*  exb      = (int2*) alloc((size_t)E_BUILD * 8);
    int2*  cse_c    = (int2*) alloc((size_t)E_COMM * 8);
    float* dinv_b   = (float*)alloc(N_BUILD * 4);
    float* dinv_c   = (float*)alloc(N_COMM * 4);
    unsigned short* cFb    = (unsigned short*)alloc((size_t)N_COMM * 32 * 2);
    unsigned short* Wt_c1  = (unsigned short*)alloc(64 * 32 * 2);
    unsigned short* Wt_c2  = (unsigned short*)alloc(64 * 64 * 2);
    unsigned short* Wt_b1  = (unsigned short*)alloc(128 * 128 * 2);
    unsigned short* Wt_b2  = (unsigned short*)alloc(64 * 128 * 2);
    unsigned short* ch_bf  = (unsigned short*)alloc((size_t)N_COMM * 64 * 2);
    unsigned short* cx1_bf = (unsigned short*)alloc((size_t)N_COMM * 64 * 2);
    unsigned short* cx2_bf = (unsigned short*)alloc((size_t)N_COMM * 64 * 2);
    unsigned short* bFl    = (unsigned short*)alloc((size_t)N_BUILD * 64 * 2);
    int4*  nmeta           = (int4*)          alloc((size_t)N_BUILD * 16);
    unsigned short* y1_bf  = (unsigned short*)alloc((size_t)N_BUILD * 128 * 2);
    unsigned short* h2_bf  = (unsigned short*)alloc((size_t)N_BUILD * 64 * 2);
    float* Dh = (float*)alloc((size_t)N_BUILD * 2 * 4);

    // ---- init + CSR build (rowptr/cursor/deg for both graphs) ----
    init_k<<<g1(INIT_TOT), 256, 0, stream>>>(cnt_b, cnt_c, out,
                                             cF, cFb, W_c1, Wt_c1, W_c2, Wt_c2, W_b1, Wt_b1, W_b2, Wt_b2);
    hist2_k<<<g1(E_BUILD + E_COMM), 256, 0, stream>>>(cnt_b, b_dst, cnt_c, c_dst);
    scan1m_k<<<NB_B + NB_C, 256, 0, stream>>>(cnt_b, rowptr_b, bsum_b, cnt_c, rowptr_c, bsum_c);
    scan2m_k<<<2, 256, 0, stream>>>(bsum_b, bsum_c);
    finalizem_k<<<g1(N_BUILD + N_COMM), 256, 0, stream>>>(cnt_b, rowptr_b, bsum_b, cursor_b, dinv_b,
                                                          cnt_c, rowptr_c, bsum_c, cursor_c, dinv_c);
    csr_scatterc_k<<<8 * CB_C, 256, 0, stream>>>(c_src, c_dst, cursor_c, dinv_c, cse_c);

    // ---- community GCN (2 layers) ----
    gemm_mfma_k<32, 64, true><<<dim3((N_COMM + 63) / 64), 256, 0, stream>>>(cFb, Wt_c1, ch_bf, N_COMM);
    gatherF_k<64, true><<<g1((long long)(N_COMM / 8) * 64), 256, 0, stream>>>(rowptr_c, cse_c, ch_bf, dinv_c, b_c1, cx1_bf, N_COMM / 8);
    gemm_mfma_k<64, 64, true><<<dim3((N_COMM + 63) / 64), 256, 0, stream>>>(cx1_bf, Wt_c2, ch_bf, N_COMM);
    gatherF_k<64, true><<<g1((long long)(N_COMM / 8) * 64), 256, 0, stream>>>(rowptr_c, cse_c, ch_bf, dinv_c, b_c2, cx2_bf, N_COMM / 8);

    // ---- attention scalars (pre-scaled bFl + packed node meta) ----
    attscal_k<<<g1((long long)N_BUILD * 8), 256, 0, stream>>>(bF, cx2_bf, map, l2g, W_at, b_at,
                                                              dinv_b, bFl, nmeta, N_BUILD);

    // ---- building CSR scatter (packs per-edge scalars as streaming payloads) ----
    csr_scatterb_k<<<8 * CB_B, 256, 0, stream>>>(b_src, b_dst, cursor_b, dinv_b, nmeta, cse_b, exb);

    // ---- layer-1 aggregation over fused features (zero random metadata) ----
    agg1_k<<<g1((long long)(N_BUILD / 4) * 64), 256, 0, stream>>>(rowptr_b, cse_b, exb, bFl, cx2_bf,
                                                                  nmeta, y1_bf, N_BUILD / 4);

    // ---- h2 = relu(y1@W1 + b1) @ W2 ----
    gemm2x_k<<<dim3(N_BUILD / 64), 256, 0, stream>>>(y1_bf, Wt_b1, b_b1, Wt_b2, h2_bf);

    // ---- building layer 2 aggregation + relu + layer-3 XW -> Dh ----
    gather64_dot_k<<<g1((long long)(N_BUILD / 8) * 64), 256, 0, stream>>>(rowptr_b, cse_b, h2_bf, dinv_b, b_b2, W_b3, Dh, N_BUILD / 8);

    // ---- building layer 3 aggregation + log-softmax + scatter ----
    gather2_logsm_k<<<g1(N_BUILD), 256, 0, stream>>>(rowptr_b, cse_b, Dh, dinv_b, b_b3, l2g, out, N_BUILD);
}

// Round 13
// 361.241 us; speedup vs baseline: 1.1211x; 1.1211x over previous
//
#include <hip/hip_runtime.h>
#include <hip/hip_bf16.h>
#include <math.h>

#define N_BUILD 200000
#define N_COMM  10000
#define E_BUILD 1200000
#define E_COMM  160000
#define NB_B 196   // scan blocks for building (200000/1024 rounded up)
#define NB_C 10
#define CHUNK 2048
#define CB_B ((E_BUILD + CHUNK - 1) / CHUNK)   // 586
#define CB_C ((E_COMM  + CHUNK - 1) / CHUNK)   // 79

typedef __bf16 bf16x8 __attribute__((ext_vector_type(8)));
typedef float  f32x4  __attribute__((ext_vector_type(4)));

// ---------------- bf16 helpers (RNE) ----------------
__device__ __forceinline__ unsigned short f2b(float f) {
    unsigned int u = __builtin_bit_cast(unsigned int, f);
    u += 0x7fffu + ((u >> 16) & 1u);
    return (unsigned short)(u >> 16);
}
__device__ __forceinline__ float b2f(unsigned short h) {
    unsigned int u = ((unsigned int)h) << 16;
    return __builtin_bit_cast(float, u);
}
__device__ __forceinline__ unsigned int pk2(float a, float b) {
    return (unsigned int)f2b(a) | ((unsigned int)f2b(b) << 16);
}
__device__ __forceinline__ void up8(uint4 v, float* r) {
    r[0] = b2f((unsigned short)v.x); r[1] = b2f((unsigned short)(v.x >> 16));
    r[2] = b2f((unsigned short)v.y); r[3] = b2f((unsigned short)(v.y >> 16));
    r[4] = b2f((unsigned short)v.z); r[5] = b2f((unsigned short)(v.z >> 16));
    r[6] = b2f((unsigned short)v.w); r[7] = b2f((unsigned short)(v.w >> 16));
}

// ---------------- merged init: zero counts + out prefill + all weight prep ----------------
#define INIT_TOT (N_BUILD + N_COMM + 2 * N_BUILD + N_COMM * 32 + 2048 + 4096 + 16384 + 8192)
__global__ __launch_bounds__(256) void init_k(int* cnt_b, int* cnt_c, float* out,
                                              const float* __restrict__ cF, unsigned short* __restrict__ cFb,
                                              const float* __restrict__ W_c1, unsigned short* __restrict__ Wt_c1,
                                              const float* __restrict__ W_c2, unsigned short* __restrict__ Wt_c2,
                                              const float* __restrict__ W_b1, unsigned short* __restrict__ Wt_b1,
                                              const float* __restrict__ W_b2, unsigned short* __restrict__ Wt_b2) {
    int i = blockIdx.x * blockDim.x + threadIdx.x;
    if (i < N_BUILD) { cnt_b[i] = 0; return; }
    i -= N_BUILD;
    if (i < N_COMM) { cnt_c[i] = 0; return; }
    i -= N_COMM;
    if (i < 2 * N_BUILD) { out[i] = -0.69314718056f; return; }
    i -= 2 * N_BUILD;
    if (i < N_COMM * 32) { cFb[i] = f2b(cF[i]); return; }
    i -= N_COMM * 32;
    if (i < 2048) { Wt_c1[(i % 64) * 32 + i / 64] = f2b(W_c1[i]); return; }
    i -= 2048;
    if (i < 4096) { Wt_c2[(i % 64) * 64 + i / 64] = f2b(W_c2[i]); return; }
    i -= 4096;
    if (i < 16384) { Wt_b1[(i % 128) * 128 + i / 128] = f2b(W_b1[i]); return; }
    i -= 16384;
    if (i < 8192) { Wt_b2[(i % 64) * 128 + i / 64] = f2b(W_b2[i]); }
}

// ---------------- merged CSR build kernels ----------------

__global__ __launch_bounds__(256) void hist2_k(int* cnt_b, const int* __restrict__ b_dst,
                                               int* cnt_c, const int* __restrict__ c_dst) {
    int i = blockIdx.x * blockDim.x + threadIdx.x;
    if (i < E_BUILD) atomicAdd(&cnt_b[b_dst[i]], 1);
    else if (i < E_BUILD + E_COMM) atomicAdd(&cnt_c[c_dst[i - E_BUILD]], 1);
}

__global__ __launch_bounds__(256) void scan1m_k(const int* __restrict__ cnt_b, int* __restrict__ ex_b, int* __restrict__ bs_b,
                                                const int* __restrict__ cnt_c, int* __restrict__ ex_c, int* __restrict__ bs_c) {
    __shared__ int sdata[256];
    const int tid = threadIdx.x;
    const int* cnt; int* ex; int* bs; int n, blk;
    if ((int)blockIdx.x < NB_B) { cnt = cnt_b; ex = ex_b; bs = bs_b; n = N_BUILD; blk = blockIdx.x; }
    else                        { cnt = cnt_c; ex = ex_c; bs = bs_c; n = N_COMM;  blk = blockIdx.x - NB_B; }
    const int base = blk * 1024 + tid * 4;
    int v[4]; int s = 0;
#pragma unroll
    for (int j = 0; j < 4; ++j) { v[j] = (base + j < n) ? cnt[base + j] : 0; s += v[j]; }
    sdata[tid] = s; __syncthreads();
    for (int off = 1; off < 256; off <<= 1) {
        int t = (tid >= off) ? sdata[tid - off] : 0;
        __syncthreads();
        sdata[tid] += t;
        __syncthreads();
    }
    if (tid == 255) bs[blk] = sdata[255];
    int run = sdata[tid] - s;
#pragma unroll
    for (int j = 0; j < 4; ++j) { if (base + j < n) ex[base + j] = run; run += v[j]; }
}

__global__ __launch_bounds__(256) void scan2m_k(int* bs_b, int* bs_c) {
    __shared__ int sdata[256];
    int* bs = (blockIdx.x == 0) ? bs_b : bs_c;
    int nb  = (blockIdx.x == 0) ? NB_B : NB_C;
    const int tid = threadIdx.x;
    int v = (tid < nb) ? bs[tid] : 0;
    sdata[tid] = v; __syncthreads();
    for (int off = 1; off < 256; off <<= 1) {
        int t = (tid >= off) ? sdata[tid - off] : 0;
        __syncthreads();
        sdata[tid] += t;
        __syncthreads();
    }
    if (tid < nb) bs[tid] = sdata[tid] - v;
}

__global__ __launch_bounds__(256) void finalizem_k(const int* __restrict__ cnt_b, int* rp_b, const int* __restrict__ bo_b,
                                                   int* cur_b, float* di_b,
                                                   const int* __restrict__ cnt_c, int* rp_c, const int* __restrict__ bo_c,
                                                   int* cur_c, float* di_c) {
    int i = blockIdx.x * blockDim.x + threadIdx.x;
    if (i < N_BUILD) {
        int cc = cnt_b[i];
        int r = rp_b[i] + bo_b[i >> 10];
        rp_b[i] = r; cur_b[i] = r; di_b[i] = 1.0f / (float)(cc + 1);
        if (i == 0) { rp_b[N_BUILD] = E_BUILD; rp_c[N_COMM] = E_COMM; }
    } else if (i < N_BUILD + N_COMM) {
        int ic = i - N_BUILD;
        int cc = cnt_c[ic];
        int r = rp_c[ic] + bo_c[ic >> 10];
        rp_c[ic] = r; cur_c[ic] = r; di_c[ic] = 1.0f / (float)(cc + 1);
    }
}

// XCD-range-partitioned CSR scatter (kills partial-dirty-line write amplification).
template<int NDIV>
__device__ __forceinline__ void scatter_part(const int* __restrict__ src, const int* __restrict__ dst,
                                             int* cur, const float* __restrict__ di,
                                             int2* __restrict__ cse, int E, int cid, int x) {
    int base = cid * CHUNK + threadIdx.x;
#pragma unroll
    for (int j = 0; j < CHUNK / 256; ++j, base += 256) {
        if (base < E) {
            int d = dst[base];
            if ((unsigned)d / (unsigned)NDIV == (unsigned)x) {
                int s = src[base];
                int pos = atomicAdd(&cur[d], 1);
                cse[pos] = make_int2(s, __float_as_int(sqrtf(di[s] * di[d])));
            }
        }
    }
}

__global__ __launch_bounds__(256) void csr_scatterp_k(const int* __restrict__ b_src, const int* __restrict__ b_dst,
                                                      int* cur_b, const float* __restrict__ di_b, int2* __restrict__ cse_b,
                                                      const int* __restrict__ c_src, const int* __restrict__ c_dst,
                                                      int* cur_c, const float* __restrict__ di_c, int2* __restrict__ cse_c) {
    int bid = blockIdx.x;
    if (bid < 8 * CB_B) {
        scatter_part<N_BUILD / 8>(b_src, b_dst, cur_b, di_b, cse_b, E_BUILD, bid >> 3, bid & 7);
    } else {
        bid -= 8 * CB_B;
        scatter_part<N_COMM / 8>(c_src, c_dst, cur_c, di_c, cse_c, E_COMM, bid >> 3, bid & 7);
    }
}

// ---------------- MFMA GEMM: H[M][N] (bf16) = X[M][K] (bf16) @ Wt[N][K]^T ----------------
template<int K, int N, bool GUARD>
__global__ __launch_bounds__(256) void gemm_mfma_k(const unsigned short* __restrict__ X,
                                                   const unsigned short* __restrict__ Wt,
                                                   unsigned short* __restrict__ H, int M) {
    constexpr int GPR = K / 8;
    __shared__ unsigned short sA[64 * K];
    __shared__ unsigned short sB[N * K];
    const int tid  = threadIdx.x;
    const int row0 = blockIdx.x * 64;

    for (int idx = tid; idx < 64 * GPR; idx += 256) {
        int r = idx / GPR, g = idx % GPR;
        uint4 v = make_uint4(0u, 0u, 0u, 0u);
        if (!GUARD || row0 + r < M)
            v = *(const uint4*)&X[(size_t)(row0 + r) * K + g * 8];
        int gs = g ^ (r & (GPR - 1));
        *(uint4*)&sA[r * K + gs * 8] = v;
    }
    for (int idx = tid; idx < N * GPR; idx += 256) {
        int r = idx / GPR, g = idx % GPR;
        uint4 v = *(const uint4*)&Wt[(size_t)r * K + g * 8];
        int gs = g ^ (r & (GPR - 1));
        *(uint4*)&sB[r * K + gs * 8] = v;
    }
    __syncthreads();

    const int wave = tid >> 6, lane = tid & 63;
    const int rA = wave * 16 + (lane & 15);
    const int kg = lane >> 4;

    f32x4 zero = {0.f, 0.f, 0.f, 0.f};
    f32x4 acc[N / 16];
#pragma unroll
    for (int t = 0; t < N / 16; ++t) acc[t] = zero;

#pragma unroll
    for (int ks = 0; ks < K / 32; ++ks) {
        int gA = (ks * 4 + kg) ^ (rA & (GPR - 1));
        bf16x8 a = *(const bf16x8*)&sA[rA * K + gA * 8];
#pragma unroll
        for (int t = 0; t < N / 16; ++t) {
            int rB = t * 16 + (lane & 15);
            int gB = (ks * 4 + kg) ^ (rB & (GPR - 1));
            bf16x8 b = *(const bf16x8*)&sB[rB * K + gB * 8];
            acc[t] = __builtin_amdgcn_mfma_f32_16x16x32_bf16(a, b, acc[t], 0, 0, 0);
        }
    }

    const int crow = wave * 16 + (lane >> 4) * 4;
    const int ccol = lane & 15;
#pragma unroll
    for (int t = 0; t < N / 16; ++t) {
#pragma unroll
        for (int j = 0; j < 4; ++j) {
            int r = row0 + crow + j;
            if (!GUARD || r < M)
                H[(size_t)r * N + t * 16 + ccol] = f2b(acc[t][j]);
        }
    }
}

// ---------------- fused attention + building GEMM layer 1 (K=N=128) ----------------
// No LDS B-tile: Wt_b1 (32KB) is read directly from global (L1/L2-resident).
// Each wave writes and reads only its OWN 16 sA rows -> no inter-phase barrier.
__global__ __launch_bounds__(256) void gemm_att_k(const float* __restrict__ bF,
                                                  const unsigned short* __restrict__ cx,
                                                  const int* __restrict__ map,
                                                  const int* __restrict__ l2g,
                                                  const float* __restrict__ Watt,  // [128][2]
                                                  const float* __restrict__ batt,  // [2]
                                                  const unsigned short* __restrict__ Wt,  // [128][128]
                                                  unsigned short* __restrict__ H) {
    constexpr int K = 128, N = 128, GPR = 16;
    __shared__ unsigned short sA[64 * K];
    __shared__ float sWt[256];
    const int tid = threadIdx.x;
    const int row0 = blockIdx.x * 64;
    sWt[tid] = Watt[tid];
    __syncthreads();   // only barrier: sWt ready before att phase
    {
        const int r = tid >> 2, j = tid & 3;   // N_BUILD % 64 == 0 -> no guard
        const int g = l2g[row0 + r];
        float vals[32];
        if (j < 2) {
            const float* f1 = &bF[(size_t)g * 64 + j * 32];
#pragma unroll
            for (int t = 0; t < 8; ++t) {
                float4 v = *(const float4*)&f1[t * 4];
                vals[t*4+0]=v.x; vals[t*4+1]=v.y; vals[t*4+2]=v.z; vals[t*4+3]=v.w;
            }
        } else {
            const unsigned short* f2 = &cx[(size_t)map[g] * 64 + (j & 1) * 32];
#pragma unroll
            for (int t = 0; t < 4; ++t) {
                uint4 u = *(const uint4*)&f2[t * 8];
                up8(u, &vals[t * 8]);
            }
        }
        float l0 = 0.f, l1 = 0.f;
        const int ch0 = j * 32;
#pragma unroll
        for (int t = 0; t < 32; ++t) {
            l0 = fmaf(vals[t], sWt[(ch0 + t) * 2 + 0], l0);
            l1 = fmaf(vals[t], sWt[(ch0 + t) * 2 + 1], l1);
        }
        l0 += __shfl_xor(l0, 1, 4); l0 += __shfl_xor(l0, 2, 4);
        l1 += __shfl_xor(l1, 1, 4); l1 += __shfl_xor(l1, 2, 4);
        l0 += batt[0]; l1 += batt[1];
        float mm = fmaxf(l0, l1);
        float e0 = __expf(l0 - mm), e1 = __expf(l1 - mm);
        float a = ((j < 2) ? e0 : e1) / (e0 + e1);
#pragma unroll
        for (int t = 0; t < 4; ++t) {
            uint4 o;
            o.x = pk2(vals[t*8+0]*a, vals[t*8+1]*a);
            o.y = pk2(vals[t*8+2]*a, vals[t*8+3]*a);
            o.z = pk2(vals[t*8+4]*a, vals[t*8+5]*a);
            o.w = pk2(vals[t*8+6]*a, vals[t*8+7]*a);
            int gi = j * 4 + t;
            int gs = gi ^ (r & (GPR - 1));
            *(uint4*)&sA[r * K + gs * 8] = o;
        }
    }
    // no barrier: wave-local sA rows, LDS ops in-order within a wave
    const int wave = tid >> 6, lane = tid & 63;
    const int rA = wave * 16 + (lane & 15);
    const int kg = lane >> 4;
    f32x4 zero = {0.f, 0.f, 0.f, 0.f};
    f32x4 acc[8];
#pragma unroll
    for (int t = 0; t < 8; ++t) acc[t] = zero;
#pragma unroll
    for (int ks = 0; ks < 4; ++ks) {
        int gA = (ks * 4 + kg) ^ (rA & 15);
        bf16x8 a = *(const bf16x8*)&sA[rA * K + gA * 8];
#pragma unroll
        for (int t = 0; t < 8; ++t) {
            int rB = t * 16 + (lane & 15);
            bf16x8 b = *(const bf16x8*)&Wt[(size_t)rB * K + (ks * 4 + kg) * 8];
            acc[t] = __builtin_amdgcn_mfma_f32_16x16x32_bf16(a, b, acc[t], 0, 0, 0);
        }
    }
    const int crow = wave * 16 + (lane >> 4) * 4;
    const int ccol = lane & 15;
#pragma unroll
    for (int t = 0; t < 8; ++t)
#pragma unroll
        for (int jj = 0; jj < 4; ++jj)
            H[(size_t)(row0 + crow + jj) * N + t * 16 + ccol] = f2b(acc[t][jj]);
}

// ---------------- fused building layer-1 aggregation + layer-2 GEMM ----------------
// Block handles 64 nodes: (1) each wave gather-aggregates its own 16 rows of
// o1 = relu(agg(h1)+h1/deg+b1) into LDS, (2) MFMA o1 @ Wt_b2 -> h2[64][64].
// Wt_b2 (16KB) read directly from global (L1-resident) -> no sB, NO barriers:
// waves run fully independently (no straggler sync on degree variance).
__global__ __launch_bounds__(256) void gather_gemm_k(const int* __restrict__ rowptr,
                                                     const int2* __restrict__ cse,
                                                     const unsigned short* __restrict__ h,     // h1 [N][128]
                                                     const float* __restrict__ dinv,
                                                     const float* __restrict__ bias,           // b_b1 [128]
                                                     const unsigned short* __restrict__ Wt,    // Wt_b2 [64][128]
                                                     unsigned short* __restrict__ H) {         // h2 [N][64]
    constexpr int K = 128, GPR = 16;
    __shared__ unsigned short sA[64 * K];
    const int tid = threadIdx.x;
    const int row0 = blockIdx.x * 64;
    const int lane = tid & 63;
    const int wave = tid >> 6;
    const int slot = lane >> 4;          // node slot within sub-batch
    const int c = (lane & 15) * 8;       // channel base (8 ch = 16B per lane)
#pragma unroll
    for (int sb = 0; sb < 4; ++sb) {
        const int r = wave * 16 + sb * 4 + slot;   // LDS row, within this wave's 16 rows
        const int node = row0 + r;
        int beg = rowptr[node], end = rowptr[node + 1];
        uint4 hv = *(const uint4*)&h[(size_t)node * K + c];
        float iv = dinv[node];
        float4 bb0 = *(const float4*)&bias[c];
        float4 bb1 = *(const float4*)&bias[c + 4];
        float acc[8];
#pragma unroll
        for (int i = 0; i < 8; ++i) acc[i] = 0.f;
        for (int p = beg; p < end; p += 8) {
            int2 q[8]; uint4 v[8];
#pragma unroll
            for (int t = 0; t < 8; ++t) { int e = p + t; q[t] = cse[e < end ? e : 0]; }
#pragma unroll
            for (int t = 0; t < 8; ++t) v[t] = *(const uint4*)&h[(size_t)q[t].x * K + c];
#pragma unroll
            for (int t = 0; t < 8; ++t) {
                float w = (p + t < end) ? __int_as_float(q[t].y) : 0.f;
                float rr[8]; up8(v[t], rr);
#pragma unroll
                for (int i = 0; i < 8; ++i) acc[i] = fmaf(rr[i], w, acc[i]);
            }
        }
        float hr[8]; up8(hv, hr);
        float o[8];
        o[0] = fmaf(hr[0], iv, acc[0]) + bb0.x; o[1] = fmaf(hr[1], iv, acc[1]) + bb0.y;
        o[2] = fmaf(hr[2], iv, acc[2]) + bb0.z; o[3] = fmaf(hr[3], iv, acc[3]) + bb0.w;
        o[4] = fmaf(hr[4], iv, acc[4]) + bb1.x; o[5] = fmaf(hr[5], iv, acc[5]) + bb1.y;
        o[6] = fmaf(hr[6], iv, acc[6]) + bb1.z; o[7] = fmaf(hr[7], iv, acc[7]) + bb1.w;
#pragma unroll
        for (int i = 0; i < 8; ++i) o[i] = fmaxf(o[i], 0.f);
        uint4 ov;
        ov.x = pk2(o[0], o[1]); ov.y = pk2(o[2], o[3]);
        ov.z = pk2(o[4], o[5]); ov.w = pk2(o[6], o[7]);
        const int g = lane & 15;
        const int gs = g ^ (r & (GPR - 1));
        *(uint4*)&sA[r * K + gs * 8] = ov;
    }
    // no barrier: this wave's MFMA reads only this wave's 16 sA rows
    const int rA = wave * 16 + (lane & 15);
    const int kg = lane >> 4;
    f32x4 zero = {0.f, 0.f, 0.f, 0.f};
    f32x4 acc[4];
#pragma unroll
    for (int t = 0; t < 4; ++t) acc[t] = zero;
#pragma unroll
    for (int ks = 0; ks < 4; ++ks) {
        int gA = (ks * 4 + kg) ^ (rA & (GPR - 1));
        bf16x8 a = *(const bf16x8*)&sA[rA * K + gA * 8];
#pragma unroll
        for (int t = 0; t < 4; ++t) {
            int rB = t * 16 + (lane & 15);
            bf16x8 b = *(const bf16x8*)&Wt[(size_t)rB * K + (ks * 4 + kg) * 8];
            acc[t] = __builtin_amdgcn_mfma_f32_16x16x32_bf16(a, b, acc[t], 0, 0, 0);
        }
    }
    const int crow = wave * 16 + (lane >> 4) * 4;
    const int ccol = lane & 15;
#pragma unroll
    for (int t = 0; t < 4; ++t)
#pragma unroll
        for (int jj = 0; jj < 4; ++jj)
            H[(size_t)(row0 + crow + jj) * 64 + t * 16 + ccol] = f2b(acc[t][jj]);
}

// ---------------- gathers: deep lane-split node packing ----------------
template<int F, bool RELU>
__global__ __launch_bounds__(256) void gatherF_k(const int* __restrict__ rowptr,
                                                 const int2* __restrict__ cse,
                                                 const unsigned short* __restrict__ h,
                                                 const float* __restrict__ dinv,
                                                 const float* __restrict__ bias,
                                                 unsigned short* __restrict__ out, int nGrp) {
    constexpr int LPN = F / 8;
    constexpr int NPW = 64 / LPN;
    int wid = (blockIdx.x * blockDim.x + threadIdx.x) >> 6;
    int lane = threadIdx.x & 63;
    if (wid >= nGrp) return;
    int node = wid * NPW + lane / LPN;
    int c = (lane % LPN) * 8;
    int beg = rowptr[node], end = rowptr[node + 1];
    uint4 hv = *(const uint4*)&h[(size_t)node * F + c];
    float iv = dinv[node];
    float4 bb0 = *(const float4*)&bias[c];
    float4 bb1 = *(const float4*)&bias[c + 4];
    float acc[8];
#pragma unroll
    for (int i = 0; i < 8; ++i) acc[i] = 0.f;
    for (int p = beg; p < end; p += 8) {
        int2 q[8]; uint4 v[8];
#pragma unroll
        for (int t = 0; t < 8; ++t) { int e = p + t; q[t] = cse[e < end ? e : 0]; }
#pragma unroll
        for (int t = 0; t < 8; ++t) v[t] = *(const uint4*)&h[(size_t)q[t].x * F + c];
#pragma unroll
        for (int t = 0; t < 8; ++t) {
            float w = (p + t < end) ? __int_as_float(q[t].y) : 0.f;
            float r[8]; up8(v[t], r);
#pragma unroll
            for (int i = 0; i < 8; ++i) acc[i] = fmaf(r[i], w, acc[i]);
        }
    }
    float hr[8]; up8(hv, hr);
    float o[8];
    o[0] = fmaf(hr[0], iv, acc[0]) + bb0.x; o[1] = fmaf(hr[1], iv, acc[1]) + bb0.y;
    o[2] = fmaf(hr[2], iv, acc[2]) + bb0.z; o[3] = fmaf(hr[3], iv, acc[3]) + bb0.w;
    o[4] = fmaf(hr[4], iv, acc[4]) + bb1.x; o[5] = fmaf(hr[5], iv, acc[5]) + bb1.y;
    o[6] = fmaf(hr[6], iv, acc[6]) + bb1.z; o[7] = fmaf(hr[7], iv, acc[7]) + bb1.w;
    if (RELU) {
#pragma unroll
        for (int i = 0; i < 8; ++i) o[i] = fmaxf(o[i], 0.f);
    }
    uint4 ov;
    ov.x = pk2(o[0], o[1]); ov.y = pk2(o[2], o[3]);
    ov.z = pk2(o[4], o[5]); ov.w = pk2(o[6], o[7]);
    *(uint4*)&out[(size_t)node * F + c] = ov;
}

// building layer-2 gather fused with layer-3 XW (64 -> 2): 8 nodes/wave, 8 lanes/node.
__global__ __launch_bounds__(256) void gather64_dot_k(const int* __restrict__ rowptr,
                                                      const int2* __restrict__ cse,
                                                      const unsigned short* __restrict__ h,
                                                      const float* __restrict__ dinv,
                                                      const float* __restrict__ bias,
                                                      const float* __restrict__ W3,  // [64][2]
                                                      float* __restrict__ Dh, int nOct) {
    int wid = (blockIdx.x * blockDim.x + threadIdx.x) >> 6;
    int lane = threadIdx.x & 63;
    if (wid >= nOct) return;
    int node = wid * 8 + (lane >> 3);
    int sl = lane & 7, c = sl * 8;
    int beg = rowptr[node], end = rowptr[node + 1];
    uint4 hv = *(const uint4*)&h[(size_t)node * 64 + c];
    float iv = dinv[node];
    float4 bb0 = *(const float4*)&bias[c];
    float4 bb1 = *(const float4*)&bias[c + 4];
    float4 w4[4];
#pragma unroll
    for (int i = 0; i < 4; ++i) w4[i] = *(const float4*)&W3[c * 2 + i * 4];
    float acc[8];
#pragma unroll
    for (int i = 0; i < 8; ++i) acc[i] = 0.f;
    for (int p = beg; p < end; p += 8) {
        int2 q[8]; uint4 v[8];
#pragma unroll
        for (int t = 0; t < 8; ++t) { int e = p + t; q[t] = cse[e < end ? e : 0]; }
#pragma unroll
        for (int t = 0; t < 8; ++t) v[t] = *(const uint4*)&h[(size_t)q[t].x * 64 + c];
#pragma unroll
        for (int t = 0; t < 8; ++t) {
            float w = (p + t < end) ? __int_as_float(q[t].y) : 0.f;
            float r[8]; up8(v[t], r);
#pragma unroll
            for (int i = 0; i < 8; ++i) acc[i] = fmaf(r[i], w, acc[i]);
        }
    }
    float hr[8]; up8(hv, hr);
    float o[8];
    o[0] = fmaf(hr[0], iv, acc[0]) + bb0.x; o[1] = fmaf(hr[1], iv, acc[1]) + bb0.y;
    o[2] = fmaf(hr[2], iv, acc[2]) + bb0.z; o[3] = fmaf(hr[3], iv, acc[3]) + bb0.w;
    o[4] = fmaf(hr[4], iv, acc[4]) + bb1.x; o[5] = fmaf(hr[5], iv, acc[5]) + bb1.y;
    o[6] = fmaf(hr[6], iv, acc[6]) + bb1.z; o[7] = fmaf(hr[7], iv, acc[7]) + bb1.w;
#pragma unroll
    for (int i = 0; i < 8; ++i) o[i] = fmaxf(o[i], 0.f);
    float d0 = 0.f, d1 = 0.f;
#pragma unroll
    for (int i = 0; i < 4; ++i) {
        d0 = fmaf(o[2*i],   w4[i].x, d0); d0 = fmaf(o[2*i+1], w4[i].z, d0);
        d1 = fmaf(o[2*i],   w4[i].y, d1); d1 = fmaf(o[2*i+1], w4[i].w, d1);
    }
#pragma unroll
    for (int m = 1; m < 8; m <<= 1) {
        d0 += __shfl_xor(d0, m, 8);
        d1 += __shfl_xor(d1, m, 8);
    }
    if (sl == 0) {
        Dh[2 * (size_t)node + 0] = d0;
        Dh[2 * (size_t)node + 1] = d1;
    }
}

// final layer: gather (F=2, f32) + bias + log-softmax + scatter to global order
__global__ __launch_bounds__(256) void gather2_logsm_k(const int* __restrict__ rowptr,
                                                       const int2* __restrict__ cse,
                                                       const float* __restrict__ h2,
                                                       const float* __restrict__ dinv,
                                                       const float* __restrict__ bias,
                                                       const int* __restrict__ l2g,
                                                       float* __restrict__ out, int n) {
    int i = blockIdx.x * blockDim.x + threadIdx.x;
    if (i >= n) return;
    int beg = rowptr[i], end = rowptr[i + 1];
    float2 hv = *(const float2*)&h2[2 * (size_t)i];
    float iv = dinv[i];
    float a = 0.f, b = 0.f;
    for (int p = beg; p < end; p += 8) {
        int2 q[8]; float2 v[8];
#pragma unroll
        for (int t = 0; t < 8; ++t) { int e = p + t; q[t] = cse[e < end ? e : 0]; }
#pragma unroll
        for (int t = 0; t < 8; ++t) v[t] = *(const float2*)&h2[2 * (size_t)q[t].x];
#pragma unroll
        for (int t = 0; t < 8; ++t) {
            float w = (p + t < end) ? __int_as_float(q[t].y) : 0.f;
            a = fmaf(v[t].x, w, a);
            b = fmaf(v[t].y, w, b);
        }
    }
    a = fmaf(hv.x, iv, a) + bias[0];
    b = fmaf(hv.y, iv, b) + bias[1];
    float m = fmaxf(a, b);
    float ls = m + logf(__expf(a - m) + __expf(b - m));
    int g = l2g[i];
    out[2 * (size_t)g + 0] = a - ls;
    out[2 * (size_t)g + 1] = b - ls;
}

// ---------------- launch ----------------

static inline dim3 g1(long long n, int tpb = 256) { return dim3((unsigned)((n + tpb - 1) / tpb)); }

extern "C" void kernel_launch(void* const* d_in, const int* in_sizes, int n_in,
                              void* d_out, int out_size, void* d_ws, size_t ws_size,
                              hipStream_t stream) {
    const float* bF   = (const float*)d_in[0];
    const float* cF   = (const float*)d_in[1];
    const float* W_c1 = (const float*)d_in[2];
    const float* b_c1 = (const float*)d_in[3];
    const float* W_c2 = (const float*)d_in[4];
    const float* b_c2 = (const float*)d_in[5];
    const float* W_at = (const float*)d_in[6];
    const float* b_at = (const float*)d_in[7];
    const float* W_b1 = (const float*)d_in[8];
    const float* b_b1 = (const float*)d_in[9];
    const float* W_b2 = (const float*)d_in[10];
    const float* b_b2 = (const float*)d_in[11];
    const float* W_b3 = (const float*)d_in[12];
    const float* b_b3 = (const float*)d_in[13];
    const int* b_src = (const int*)d_in[14];
    const int* b_dst = (const int*)d_in[15];
    const int* c_src = (const int*)d_in[16];
    const int* c_dst = (const int*)d_in[17];
    const int* map   = (const int*)d_in[18];
    const int* l2g   = (const int*)d_in[19];
    float* out = (float*)d_out;

    char* p = (char*)d_ws;
    auto alloc = [&](size_t bytes) { char* q = p; p += (bytes + 15) & ~(size_t)15; return q; };
    int*   cnt_b    = (int*)  alloc(N_BUILD * 4);
    int*   rowptr_b = (int*)  alloc((N_BUILD + 4) * 4);
    int*   cursor_b = (int*)  alloc(N_BUILD * 4);
    int*   bsum_b   = (int*)  alloc(256 * 4);
    int*   cnt_c    = (int*)  alloc(N_COMM * 4);
    int*   rowptr_c = (int*)  alloc((N_COMM + 4) * 4);
    int*   cursor_c = (int*)  alloc(N_COMM * 4);
    int*   bsum_c   = (int*)  alloc(256 * 4);
    int2*  cse_b    = (int2*) alloc((size_t)E_BUILD * 8);
    int2*  cse_c    = (int2*) alloc((size_t)E_COMM * 8);
    float* dinv_b   = (float*)alloc(N_BUILD * 4);
    float* dinv_c   = (float*)alloc(N_COMM * 4);
    unsigned short* cFb    = (unsigned short*)alloc((size_t)N_COMM * 32 * 2);
    unsigned short* Wt_c1  = (unsigned short*)alloc(64 * 32 * 2);
    unsigned short* Wt_c2  = (unsigned short*)alloc(64 * 64 * 2);
    unsigned short* Wt_b1  = (unsigned short*)alloc(128 * 128 * 2);
    unsigned short* Wt_b2  = (unsigned short*)alloc(64 * 128 * 2);
    unsigned short* ch_bf  = (unsigned short*)alloc((size_t)N_COMM * 64 * 2);
    unsigned short* cx1_bf = (unsigned short*)alloc((size_t)N_COMM * 64 * 2);
    unsigned short* cx2_bf = (unsigned short*)alloc((size_t)N_COMM * 64 * 2);
    unsigned short* A_bf   = (unsigned short*)alloc((size_t)N_BUILD * 128 * 2); // h2
    unsigned short* B_bf   = (unsigned short*)alloc((size_t)N_BUILD * 128 * 2); // h1
    float* Dh = (float*)alloc((size_t)N_BUILD * 2 * 4);

    // ---- init (counts zero + out prefill + weight prep), then CSR build both graphs ----
    init_k<<<g1(INIT_TOT), 256, 0, stream>>>(cnt_b, cnt_c, out,
                                             cF, cFb, W_c1, Wt_c1, W_c2, Wt_c2, W_b1, Wt_b1, W_b2, Wt_b2);
    hist2_k<<<g1(E_BUILD + E_COMM), 256, 0, stream>>>(cnt_b, b_dst, cnt_c, c_dst);
    scan1m_k<<<NB_B + NB_C, 256, 0, stream>>>(cnt_b, rowptr_b, bsum_b, cnt_c, rowptr_c, bsum_c);
    scan2m_k<<<2, 256, 0, stream>>>(bsum_b, bsum_c);
    finalizem_k<<<g1(N_BUILD + N_COMM), 256, 0, stream>>>(cnt_b, rowptr_b, bsum_b, cursor_b, dinv_b,
                                                          cnt_c, rowptr_c, bsum_c, cursor_c, dinv_c);
    csr_scatterp_k<<<8 * (CB_B + CB_C), 256, 0, stream>>>(b_src, b_dst, cursor_b, dinv_b, cse_b,
                                                          c_src, c_dst, cursor_c, dinv_c, cse_c);

    // ---- community GCN layer 1 (32 -> 64) + relu ----
    gemm_mfma_k<32, 64, true><<<dim3((N_COMM + 63) / 64), 256, 0, stream>>>(cFb, Wt_c1, ch_bf, N_COMM);
    gatherF_k<64, true><<<g1((long long)(N_COMM / 8) * 64), 256, 0, stream>>>(rowptr_c, cse_c, ch_bf, dinv_c, b_c1, cx1_bf, N_COMM / 8);

    // ---- community GCN layer 2 (64 -> 64) + relu ----
    gemm_mfma_k<64, 64, true><<<dim3((N_COMM + 63) / 64), 256, 0, stream>>>(cx1_bf, Wt_c2, ch_bf, N_COMM);
    gatherF_k<64, true><<<g1((long long)(N_COMM / 8) * 64), 256, 0, stream>>>(rowptr_c, cse_c, ch_bf, dinv_c, b_c2, cx2_bf, N_COMM / 8);

    // ---- building layer 1 GEMM (fused attention), writes h1 ----
    gemm_att_k<<<dim3(N_BUILD / 64), 256, 0, stream>>>(bF, cx2_bf, map, l2g, W_at, b_at, Wt_b1, B_bf);

    // ---- fused: layer-1 aggregation + relu + layer-2 GEMM -> h2 (A_bf) ----
    gather_gemm_k<<<dim3(N_BUILD / 64), 256, 0, stream>>>(rowptr_b, cse_b, B_bf, dinv_b, b_b1, Wt_b2, A_bf);

    // ---- building layer 2 aggregation + relu, fused with layer-3 XW -> Dh ----
    gather64_dot_k<<<g1((long long)(N_BUILD / 8) * 64), 256, 0, stream>>>(rowptr_b, cse_b, A_bf, dinv_b, b_b2, W_b3, Dh, N_BUILD / 8);

    // ---- building layer 3 aggregation + log-softmax + scatter ----
    gather2_logsm_k<<<g1(N_BUILD), 256, 0, stream>>>(rowptr_b, cse_b, Dh, dinv_b, b_b3, l2g, out, N_BUILD);
}

// Round 14
// 337.141 us; speedup vs baseline: 1.2013x; 1.0715x over previous
//
#include <hip/hip_runtime.h>
#include <hip/hip_bf16.h>
#include <math.h>

#define N_BUILD 200000
#define N_COMM  10000
#define E_BUILD 1200000
#define E_COMM  160000
#define NB_B 196   // scan blocks for building (200000/1024 rounded up)
#define NB_C 10
#define CHUNK 2048
#define CB_B ((E_BUILD + CHUNK - 1) / CHUNK)   // 586
#define CB_C ((E_COMM  + CHUNK - 1) / CHUNK)   // 79

typedef __bf16 bf16x8 __attribute__((ext_vector_type(8)));
typedef float  f32x4  __attribute__((ext_vector_type(4)));

// ---------------- bf16 helpers (RNE) ----------------
__device__ __forceinline__ unsigned short f2b(float f) {
    unsigned int u = __builtin_bit_cast(unsigned int, f);
    u += 0x7fffu + ((u >> 16) & 1u);
    return (unsigned short)(u >> 16);
}
__device__ __forceinline__ float b2f(unsigned short h) {
    unsigned int u = ((unsigned int)h) << 16;
    return __builtin_bit_cast(float, u);
}
__device__ __forceinline__ unsigned int pk2(float a, float b) {
    return (unsigned int)f2b(a) | ((unsigned int)f2b(b) << 16);
}
__device__ __forceinline__ void up8(uint4 v, float* r) {
    r[0] = b2f((unsigned short)v.x); r[1] = b2f((unsigned short)(v.x >> 16));
    r[2] = b2f((unsigned short)v.y); r[3] = b2f((unsigned short)(v.y >> 16));
    r[4] = b2f((unsigned short)v.z); r[5] = b2f((unsigned short)(v.z >> 16));
    r[6] = b2f((unsigned short)v.w); r[7] = b2f((unsigned short)(v.w >> 16));
}

// ---------------- merged init: zero counts + out prefill + all weight prep ----------------
#define INIT_TOT (N_BUILD + N_COMM + 2 * N_BUILD + N_COMM * 32 + 2048 + 4096 + 16384 + 8192)
__global__ __launch_bounds__(256) void init_k(int* cnt_b, int* cnt_c, float* out,
                                              const float* __restrict__ cF, unsigned short* __restrict__ cFb,
                                              const float* __restrict__ W_c1, unsigned short* __restrict__ Wt_c1,
                                              const float* __restrict__ W_c2, unsigned short* __restrict__ Wt_c2,
                                              const float* __restrict__ W_b1, unsigned short* __restrict__ Wt_b1,
                                              const float* __restrict__ W_b2, unsigned short* __restrict__ Wt_b2) {
    int i = blockIdx.x * blockDim.x + threadIdx.x;
    if (i < N_BUILD) { cnt_b[i] = 0; return; }
    i -= N_BUILD;
    if (i < N_COMM) { cnt_c[i] = 0; return; }
    i -= N_COMM;
    if (i < 2 * N_BUILD) { out[i] = -0.69314718056f; return; }
    i -= 2 * N_BUILD;
    if (i < N_COMM * 32) { cFb[i] = f2b(cF[i]); return; }
    i -= N_COMM * 32;
    if (i < 2048) { Wt_c1[(i % 64) * 32 + i / 64] = f2b(W_c1[i]); return; }
    i -= 2048;
    if (i < 4096) { Wt_c2[(i % 64) * 64 + i / 64] = f2b(W_c2[i]); return; }
    i -= 4096;
    if (i < 16384) { Wt_b1[(i % 128) * 128 + i / 128] = f2b(W_b1[i]); return; }
    i -= 16384;
    if (i < 8192) { Wt_b2[(i % 64) * 128 + i / 64] = f2b(W_b2[i]); }
}

// ---------------- merged CSR build kernels ----------------

__global__ __launch_bounds__(256) void hist2_k(int* cnt_b, const int* __restrict__ b_dst,
                                               int* cnt_c, const int* __restrict__ c_dst) {
    int i = blockIdx.x * blockDim.x + threadIdx.x;
    if (i < E_BUILD) atomicAdd(&cnt_b[b_dst[i]], 1);
    else if (i < E_BUILD + E_COMM) atomicAdd(&cnt_c[c_dst[i - E_BUILD]], 1);
}

__global__ __launch_bounds__(256) void scan1m_k(const int* __restrict__ cnt_b, int* __restrict__ ex_b, int* __restrict__ bs_b,
                                                const int* __restrict__ cnt_c, int* __restrict__ ex_c, int* __restrict__ bs_c) {
    __shared__ int sdata[256];
    const int tid = threadIdx.x;
    const int* cnt; int* ex; int* bs; int n, blk;
    if ((int)blockIdx.x < NB_B) { cnt = cnt_b; ex = ex_b; bs = bs_b; n = N_BUILD; blk = blockIdx.x; }
    else                        { cnt = cnt_c; ex = ex_c; bs = bs_c; n = N_COMM;  blk = blockIdx.x - NB_B; }
    const int base = blk * 1024 + tid * 4;
    int v[4]; int s = 0;
#pragma unroll
    for (int j = 0; j < 4; ++j) { v[j] = (base + j < n) ? cnt[base + j] : 0; s += v[j]; }
    sdata[tid] = s; __syncthreads();
    for (int off = 1; off < 256; off <<= 1) {
        int t = (tid >= off) ? sdata[tid - off] : 0;
        __syncthreads();
        sdata[tid] += t;
        __syncthreads();
    }
    if (tid == 255) bs[blk] = sdata[255];
    int run = sdata[tid] - s;
#pragma unroll
    for (int j = 0; j < 4; ++j) { if (base + j < n) ex[base + j] = run; run += v[j]; }
}

__global__ __launch_bounds__(256) void scan2m_k(int* bs_b, int* bs_c) {
    __shared__ int sdata[256];
    int* bs = (blockIdx.x == 0) ? bs_b : bs_c;
    int nb  = (blockIdx.x == 0) ? NB_B : NB_C;
    const int tid = threadIdx.x;
    int v = (tid < nb) ? bs[tid] : 0;
    sdata[tid] = v; __syncthreads();
    for (int off = 1; off < 256; off <<= 1) {
        int t = (tid >= off) ? sdata[tid - off] : 0;
        __syncthreads();
        sdata[tid] += t;
        __syncthreads();
    }
    if (tid < nb) bs[tid] = sdata[tid] - v;
}

// also emits sqd[i] = sqrt(dinv[i]) so consumers reconstruct w = sqd[s]*sqd[d]
__global__ __launch_bounds__(256) void finalizem_k(const int* __restrict__ cnt_b, int* rp_b, const int* __restrict__ bo_b,
                                                   int* cur_b, float* di_b, float* sq_b,
                                                   const int* __restrict__ cnt_c, int* rp_c, const int* __restrict__ bo_c,
                                                   int* cur_c, float* di_c, float* sq_c) {
    int i = blockIdx.x * blockDim.x + threadIdx.x;
    if (i < N_BUILD) {
        int cc = cnt_b[i];
        int r = rp_b[i] + bo_b[i >> 10];
        float di = 1.0f / (float)(cc + 1);
        rp_b[i] = r; cur_b[i] = r; di_b[i] = di; sq_b[i] = sqrtf(di);
        if (i == 0) { rp_b[N_BUILD] = E_BUILD; rp_c[N_COMM] = E_COMM; }
    } else if (i < N_BUILD + N_COMM) {
        int ic = i - N_BUILD;
        int cc = cnt_c[ic];
        int r = rp_c[ic] + bo_c[ic >> 10];
        float di = 1.0f / (float)(cc + 1);
        rp_c[ic] = r; cur_c[ic] = r; di_c[ic] = di; sq_c[ic] = sqrtf(di);
    }
}

// XCD-range-partitioned CSR scatter — 4B payload (src only): halves scattered bytes,
// halving partial-dirty-line write amplification. w reconstructed by consumers.
template<int NDIV>
__device__ __forceinline__ void scatter_part(const int* __restrict__ src, const int* __restrict__ dst,
                                             int* cur, int* __restrict__ csrc, int E, int cid, int x) {
    int base = cid * CHUNK + threadIdx.x;
#pragma unroll
    for (int j = 0; j < CHUNK / 256; ++j, base += 256) {
        if (base < E) {
            int d = dst[base];
            if ((unsigned)d / (unsigned)NDIV == (unsigned)x) {
                int pos = atomicAdd(&cur[d], 1);
                csrc[pos] = src[base];
            }
        }
    }
}

__global__ __launch_bounds__(256) void csr_scatterp_k(const int* __restrict__ b_src, const int* __restrict__ b_dst,
                                                      int* cur_b, int* __restrict__ csrc_b,
                                                      const int* __restrict__ c_src, const int* __restrict__ c_dst,
                                                      int* cur_c, int* __restrict__ csrc_c) {
    int bid = blockIdx.x;
    if (bid < 8 * CB_B) {
        scatter_part<N_BUILD / 8>(b_src, b_dst, cur_b, csrc_b, E_BUILD, bid >> 3, bid & 7);
    } else {
        bid -= 8 * CB_B;
        scatter_part<N_COMM / 8>(c_src, c_dst, cur_c, csrc_c, E_COMM, bid >> 3, bid & 7);
    }
}

// ---------------- MFMA GEMM: H[M][N] (bf16) = X[M][K] (bf16) @ Wt[N][K]^T ----------------
template<int K, int N, bool GUARD>
__global__ __launch_bounds__(256) void gemm_mfma_k(const unsigned short* __restrict__ X,
                                                   const unsigned short* __restrict__ Wt,
                                                   unsigned short* __restrict__ H, int M) {
    constexpr int GPR = K / 8;
    __shared__ unsigned short sA[64 * K];
    __shared__ unsigned short sB[N * K];
    const int tid  = threadIdx.x;
    const int row0 = blockIdx.x * 64;

    for (int idx = tid; idx < 64 * GPR; idx += 256) {
        int r = idx / GPR, g = idx % GPR;
        uint4 v = make_uint4(0u, 0u, 0u, 0u);
        if (!GUARD || row0 + r < M)
            v = *(const uint4*)&X[(size_t)(row0 + r) * K + g * 8];
        int gs = g ^ (r & (GPR - 1));
        *(uint4*)&sA[r * K + gs * 8] = v;
    }
    for (int idx = tid; idx < N * GPR; idx += 256) {
        int r = idx / GPR, g = idx % GPR;
        uint4 v = *(const uint4*)&Wt[(size_t)r * K + g * 8];
        int gs = g ^ (r & (GPR - 1));
        *(uint4*)&sB[r * K + gs * 8] = v;
    }
    __syncthreads();

    const int wave = tid >> 6, lane = tid & 63;
    const int rA = wave * 16 + (lane & 15);
    const int kg = lane >> 4;

    f32x4 zero = {0.f, 0.f, 0.f, 0.f};
    f32x4 acc[N / 16];
#pragma unroll
    for (int t = 0; t < N / 16; ++t) acc[t] = zero;

#pragma unroll
    for (int ks = 0; ks < K / 32; ++ks) {
        int gA = (ks * 4 + kg) ^ (rA & (GPR - 1));
        bf16x8 a = *(const bf16x8*)&sA[rA * K + gA * 8];
#pragma unroll
        for (int t = 0; t < N / 16; ++t) {
            int rB = t * 16 + (lane & 15);
            int gB = (ks * 4 + kg) ^ (rB & (GPR - 1));
            bf16x8 b = *(const bf16x8*)&sB[rB * K + gB * 8];
            acc[t] = __builtin_amdgcn_mfma_f32_16x16x32_bf16(a, b, acc[t], 0, 0, 0);
        }
    }

    const int crow = wave * 16 + (lane >> 4) * 4;
    const int ccol = lane & 15;
#pragma unroll
    for (int t = 0; t < N / 16; ++t) {
#pragma unroll
        for (int j = 0; j < 4; ++j) {
            int r = row0 + crow + j;
            if (!GUARD || r < M)
                H[(size_t)r * N + t * 16 + ccol] = f2b(acc[t][j]);
        }
    }
}

// ---------------- fused attention + building GEMM layer 1 (K=N=128), R7 form ----------------
__global__ __launch_bounds__(256) void gemm_att_k(const float* __restrict__ bF,
                                                  const unsigned short* __restrict__ cx,
                                                  const int* __restrict__ map,
                                                  const int* __restrict__ l2g,
                                                  const float* __restrict__ Watt,  // [128][2]
                                                  const float* __restrict__ batt,  // [2]
                                                  const unsigned short* __restrict__ Wt,  // [128][128]
                                                  unsigned short* __restrict__ H) {
    constexpr int K = 128, N = 128, GPR = 16;
    __shared__ unsigned short sA[64 * K];
    __shared__ unsigned short sB[N * K];
    __shared__ float sWt[256];
    const int tid = threadIdx.x;
    const int row0 = blockIdx.x * 64;
    sWt[tid] = Watt[tid];
    for (int idx = tid; idx < N * GPR; idx += 256) {
        int r = idx / GPR, g = idx % GPR;
        uint4 v = *(const uint4*)&Wt[(size_t)r * K + g * 8];
        int gs = g ^ (r & (GPR - 1));
        *(uint4*)&sB[r * K + gs * 8] = v;
    }
    __syncthreads();
    {
        const int r = tid >> 2, j = tid & 3;   // N_BUILD % 64 == 0 -> no guard
        const int g = l2g[row0 + r];
        float vals[32];
        if (j < 2) {
            const float* f1 = &bF[(size_t)g * 64 + j * 32];
#pragma unroll
            for (int t = 0; t < 8; ++t) {
                float4 v = *(const float4*)&f1[t * 4];
                vals[t*4+0]=v.x; vals[t*4+1]=v.y; vals[t*4+2]=v.z; vals[t*4+3]=v.w;
            }
        } else {
            const unsigned short* f2 = &cx[(size_t)map[g] * 64 + (j & 1) * 32];
#pragma unroll
            for (int t = 0; t < 4; ++t) {
                uint4 u = *(const uint4*)&f2[t * 8];
                up8(u, &vals[t * 8]);
            }
        }
        float l0 = 0.f, l1 = 0.f;
        const int ch0 = j * 32;
#pragma unroll
        for (int t = 0; t < 32; ++t) {
            l0 = fmaf(vals[t], sWt[(ch0 + t) * 2 + 0], l0);
            l1 = fmaf(vals[t], sWt[(ch0 + t) * 2 + 1], l1);
        }
        l0 += __shfl_xor(l0, 1, 4); l0 += __shfl_xor(l0, 2, 4);
        l1 += __shfl_xor(l1, 1, 4); l1 += __shfl_xor(l1, 2, 4);
        l0 += batt[0]; l1 += batt[1];
        float mm = fmaxf(l0, l1);
        float e0 = __expf(l0 - mm), e1 = __expf(l1 - mm);
        float a = ((j < 2) ? e0 : e1) / (e0 + e1);
#pragma unroll
        for (int t = 0; t < 4; ++t) {
            uint4 o;
            o.x = pk2(vals[t*8+0]*a, vals[t*8+1]*a);
            o.y = pk2(vals[t*8+2]*a, vals[t*8+3]*a);
            o.z = pk2(vals[t*8+4]*a, vals[t*8+5]*a);
            o.w = pk2(vals[t*8+6]*a, vals[t*8+7]*a);
            int gi = j * 4 + t;
            int gs = gi ^ (r & (GPR - 1));
            *(uint4*)&sA[r * K + gs * 8] = o;
        }
    }
    __syncthreads();
    const int wave = tid >> 6, lane = tid & 63;
    const int rA = wave * 16 + (lane & 15);
    const int kg = lane >> 4;
    f32x4 zero = {0.f, 0.f, 0.f, 0.f};
    f32x4 acc[8];
#pragma unroll
    for (int t = 0; t < 8; ++t) acc[t] = zero;
#pragma unroll
    for (int ks = 0; ks < 4; ++ks) {
        int gA = (ks * 4 + kg) ^ (rA & 15);
        bf16x8 a = *(const bf16x8*)&sA[rA * K + gA * 8];
#pragma unroll
        for (int t = 0; t < 8; ++t) {
            int rB = t * 16 + (lane & 15);
            int gB = (ks * 4 + kg) ^ (rB & 15);
            bf16x8 b = *(const bf16x8*)&sB[rB * K + gB * 8];
            acc[t] = __builtin_amdgcn_mfma_f32_16x16x32_bf16(a, b, acc[t], 0, 0, 0);
        }
    }
    const int crow = wave * 16 + (lane >> 4) * 4;
    const int ccol = lane & 15;
#pragma unroll
    for (int t = 0; t < 8; ++t)
#pragma unroll
        for (int jj = 0; jj < 4; ++jj)
            H[(size_t)(row0 + crow + jj) * N + t * 16 + ccol] = f2b(acc[t][jj]);
}

// ---------------- fused building layer-1 aggregation + layer-2 GEMM (R7 form) ----------------
__global__ __launch_bounds__(256) void gather_gemm_k(const int* __restrict__ rowptr,
                                                     const int* __restrict__ csrc,
                                                     const float* __restrict__ sqd,
                                                     const unsigned short* __restrict__ h,     // h1 [N][128]
                                                     const float* __restrict__ dinv,
                                                     const float* __restrict__ bias,           // b_b1 [128]
                                                     const unsigned short* __restrict__ Wt,    // Wt_b2 [64][128]
                                                     unsigned short* __restrict__ H) {         // h2 [N][64]
    constexpr int K = 128, N = 64, GPR = 16;
    __shared__ unsigned short sA[64 * K];
    __shared__ unsigned short sB[N * K];
    const int tid = threadIdx.x;
    const int row0 = blockIdx.x * 64;
    // stage Wt_b2 (swizzled)
    for (int idx = tid; idx < N * GPR; idx += 256) {
        int r = idx / GPR, g = idx % GPR;
        uint4 v = *(const uint4*)&Wt[(size_t)r * K + g * 8];
        int gs = g ^ (r & (GPR - 1));
        *(uint4*)&sB[r * K + gs * 8] = v;
    }
    const int lane = tid & 63;
    const int wave = tid >> 6;
    const int slot = lane >> 4;
    const int c = (lane & 15) * 8;
#pragma unroll
    for (int sb = 0; sb < 4; ++sb) {
        const int r = wave * 16 + sb * 4 + slot;
        const int node = row0 + r;
        int beg = rowptr[node], end = rowptr[node + 1];
        uint4 hv = *(const uint4*)&h[(size_t)node * K + c];
        float iv = dinv[node];
        float sqn = sqd[node];
        float4 bb0 = *(const float4*)&bias[c];
        float4 bb1 = *(const float4*)&bias[c + 4];
        float acc[8];
#pragma unroll
        for (int i = 0; i < 8; ++i) acc[i] = 0.f;
        for (int p = beg; p < end; p += 8) {
            int q[8]; uint4 v[8]; float sq[8];
#pragma unroll
            for (int t = 0; t < 8; ++t) { int e = p + t; q[t] = csrc[e < end ? e : 0]; }
#pragma unroll
            for (int t = 0; t < 8; ++t) v[t] = *(const uint4*)&h[(size_t)q[t] * K + c];
#pragma unroll
            for (int t = 0; t < 8; ++t) sq[t] = sqd[q[t]];
#pragma unroll
            for (int t = 0; t < 8; ++t) {
                float w = (p + t < end) ? sq[t] * sqn : 0.f;
                float rr[8]; up8(v[t], rr);
#pragma unroll
                for (int i = 0; i < 8; ++i) acc[i] = fmaf(rr[i], w, acc[i]);
            }
        }
        float hr[8]; up8(hv, hr);
        float o[8];
        o[0] = fmaf(hr[0], iv, acc[0]) + bb0.x; o[1] = fmaf(hr[1], iv, acc[1]) + bb0.y;
        o[2] = fmaf(hr[2], iv, acc[2]) + bb0.z; o[3] = fmaf(hr[3], iv, acc[3]) + bb0.w;
        o[4] = fmaf(hr[4], iv, acc[4]) + bb1.x; o[5] = fmaf(hr[5], iv, acc[5]) + bb1.y;
        o[6] = fmaf(hr[6], iv, acc[6]) + bb1.z; o[7] = fmaf(hr[7], iv, acc[7]) + bb1.w;
#pragma unroll
        for (int i = 0; i < 8; ++i) o[i] = fmaxf(o[i], 0.f);
        uint4 ov;
        ov.x = pk2(o[0], o[1]); ov.y = pk2(o[2], o[3]);
        ov.z = pk2(o[4], o[5]); ov.w = pk2(o[6], o[7]);
        const int g = lane & 15;
        const int gs = g ^ (r & (GPR - 1));
        *(uint4*)&sA[r * K + gs * 8] = ov;
    }
    __syncthreads();
    const int rA = wave * 16 + (lane & 15);
    const int kg = lane >> 4;
    f32x4 zero = {0.f, 0.f, 0.f, 0.f};
    f32x4 acc[4];
#pragma unroll
    for (int t = 0; t < 4; ++t) acc[t] = zero;
#pragma unroll
    for (int ks = 0; ks < 4; ++ks) {
        int gA = (ks * 4 + kg) ^ (rA & (GPR - 1));
        bf16x8 a = *(const bf16x8*)&sA[rA * K + gA * 8];
#pragma unroll
        for (int t = 0; t < 4; ++t) {
            int rB = t * 16 + (lane & 15);
            int gB = (ks * 4 + kg) ^ (rB & (GPR - 1));
            bf16x8 b = *(const bf16x8*)&sB[rB * K + gB * 8];
            acc[t] = __builtin_amdgcn_mfma_f32_16x16x32_bf16(a, b, acc[t], 0, 0, 0);
        }
    }
    const int crow = wave * 16 + (lane >> 4) * 4;
    const int ccol = lane & 15;
#pragma unroll
    for (int t = 0; t < 4; ++t)
#pragma unroll
        for (int jj = 0; jj < 4; ++jj)
            H[(size_t)(row0 + crow + jj) * 64 + t * 16 + ccol] = f2b(acc[t][jj]);
}

// ---------------- gathers: deep lane-split node packing (4B edge payload) ----------------
template<int F, bool RELU>
__global__ __launch_bounds__(256) void gatherF_k(const int* __restrict__ rowptr,
                                                 const int* __restrict__ csrc,
                                                 const float* __restrict__ sqd,
                                                 const unsigned short* __restrict__ h,
                                                 const float* __restrict__ dinv,
                                                 const float* __restrict__ bias,
                                                 unsigned short* __restrict__ out, int nGrp) {
    constexpr int LPN = F / 8;
    constexpr int NPW = 64 / LPN;
    int wid = (blockIdx.x * blockDim.x + threadIdx.x) >> 6;
    int lane = threadIdx.x & 63;
    if (wid >= nGrp) return;
    int node = wid * NPW + lane / LPN;
    int c = (lane % LPN) * 8;
    int beg = rowptr[node], end = rowptr[node + 1];
    uint4 hv = *(const uint4*)&h[(size_t)node * F + c];
    float iv = dinv[node];
    float sqn = sqd[node];
    float4 bb0 = *(const float4*)&bias[c];
    float4 bb1 = *(const float4*)&bias[c + 4];
    float acc[8];
#pragma unroll
    for (int i = 0; i < 8; ++i) acc[i] = 0.f;
    for (int p = beg; p < end; p += 8) {
        int q[8]; uint4 v[8]; float sq[8];
#pragma unroll
        for (int t = 0; t < 8; ++t) { int e = p + t; q[t] = csrc[e < end ? e : 0]; }
#pragma unroll
        for (int t = 0; t < 8; ++t) v[t] = *(const uint4*)&h[(size_t)q[t] * F + c];
#pragma unroll
        for (int t = 0; t < 8; ++t) sq[t] = sqd[q[t]];
#pragma unroll
        for (int t = 0; t < 8; ++t) {
            float w = (p + t < end) ? sq[t] * sqn : 0.f;
            float r[8]; up8(v[t], r);
#pragma unroll
            for (int i = 0; i < 8; ++i) acc[i] = fmaf(r[i], w, acc[i]);
        }
    }
    float hr[8]; up8(hv, hr);
    float o[8];
    o[0] = fmaf(hr[0], iv, acc[0]) + bb0.x; o[1] = fmaf(hr[1], iv, acc[1]) + bb0.y;
    o[2] = fmaf(hr[2], iv, acc[2]) + bb0.z; o[3] = fmaf(hr[3], iv, acc[3]) + bb0.w;
    o[4] = fmaf(hr[4], iv, acc[4]) + bb1.x; o[5] = fmaf(hr[5], iv, acc[5]) + bb1.y;
    o[6] = fmaf(hr[6], iv, acc[6]) + bb1.z; o[7] = fmaf(hr[7], iv, acc[7]) + bb1.w;
    if (RELU) {
#pragma unroll
        for (int i = 0; i < 8; ++i) o[i] = fmaxf(o[i], 0.f);
    }
    uint4 ov;
    ov.x = pk2(o[0], o[1]); ov.y = pk2(o[2], o[3]);
    ov.z = pk2(o[4], o[5]); ov.w = pk2(o[6], o[7]);
    *(uint4*)&out[(size_t)node * F + c] = ov;
}

// building layer-2 gather fused with layer-3 XW (64 -> 2): 8 nodes/wave, 8 lanes/node.
__global__ __launch_bounds__(256) void gather64_dot_k(const int* __restrict__ rowptr,
                                                      const int* __restrict__ csrc,
                                                      const float* __restrict__ sqd,
                                                      const unsigned short* __restrict__ h,
                                                      const float* __restrict__ dinv,
                                                      const float* __restrict__ bias,
                                                      const float* __restrict__ W3,  // [64][2]
                                                      float* __restrict__ Dh, int nOct) {
    int wid = (blockIdx.x * blockDim.x + threadIdx.x) >> 6;
    int lane = threadIdx.x & 63;
    if (wid >= nOct) return;
    int node = wid * 8 + (lane >> 3);
    int sl = lane & 7, c = sl * 8;
    int beg = rowptr[node], end = rowptr[node + 1];
    uint4 hv = *(const uint4*)&h[(size_t)node * 64 + c];
    float iv = dinv[node];
    float sqn = sqd[node];
    float4 bb0 = *(const float4*)&bias[c];
    float4 bb1 = *(const float4*)&bias[c + 4];
    float4 w4[4];
#pragma unroll
    for (int i = 0; i < 4; ++i) w4[i] = *(const float4*)&W3[c * 2 + i * 4];
    float acc[8];
#pragma unroll
    for (int i = 0; i < 8; ++i) acc[i] = 0.f;
    for (int p = beg; p < end; p += 8) {
        int q[8]; uint4 v[8]; float sq[8];
#pragma unroll
        for (int t = 0; t < 8; ++t) { int e = p + t; q[t] = csrc[e < end ? e : 0]; }
#pragma unroll
        for (int t = 0; t < 8; ++t) v[t] = *(const uint4*)&h[(size_t)q[t] * 64 + c];
#pragma unroll
        for (int t = 0; t < 8; ++t) sq[t] = sqd[q[t]];
#pragma unroll
        for (int t = 0; t < 8; ++t) {
            float w = (p + t < end) ? sq[t] * sqn : 0.f;
            float r[8]; up8(v[t], r);
#pragma unroll
            for (int i = 0; i < 8; ++i) acc[i] = fmaf(r[i], w, acc[i]);
        }
    }
    float hr[8]; up8(hv, hr);
    float o[8];
    o[0] = fmaf(hr[0], iv, acc[0]) + bb0.x; o[1] = fmaf(hr[1], iv, acc[1]) + bb0.y;
    o[2] = fmaf(hr[2], iv, acc[2]) + bb0.z; o[3] = fmaf(hr[3], iv, acc[3]) + bb0.w;
    o[4] = fmaf(hr[4], iv, acc[4]) + bb1.x; o[5] = fmaf(hr[5], iv, acc[5]) + bb1.y;
    o[6] = fmaf(hr[6], iv, acc[6]) + bb1.z; o[7] = fmaf(hr[7], iv, acc[7]) + bb1.w;
#pragma unroll
    for (int i = 0; i < 8; ++i) o[i] = fmaxf(o[i], 0.f);
    float d0 = 0.f, d1 = 0.f;
#pragma unroll
    for (int i = 0; i < 4; ++i) {
        d0 = fmaf(o[2*i],   w4[i].x, d0); d0 = fmaf(o[2*i+1], w4[i].z, d0);
        d1 = fmaf(o[2*i],   w4[i].y, d1); d1 = fmaf(o[2*i+1], w4[i].w, d1);
    }
#pragma unroll
    for (int m = 1; m < 8; m <<= 1) {
        d0 += __shfl_xor(d0, m, 8);
        d1 += __shfl_xor(d1, m, 8);
    }
    if (sl == 0) {
        Dh[2 * (size_t)node + 0] = d0;
        Dh[2 * (size_t)node + 1] = d1;
    }
}

// final layer: gather (F=2, f32) + bias + log-softmax + scatter to global order
__global__ __launch_bounds__(256) void gather2_logsm_k(const int* __restrict__ rowptr,
                                                       const int* __restrict__ csrc,
                                                       const float* __restrict__ sqd,
                                                       const float* __restrict__ h2,
                                                       const float* __restrict__ dinv,
                                                       const float* __restrict__ bias,
                                                       const int* __restrict__ l2g,
                                                       float* __restrict__ out, int n) {
    int i = blockIdx.x * blockDim.x + threadIdx.x;
    if (i >= n) return;
    int beg = rowptr[i], end = rowptr[i + 1];
    float2 hv = *(const float2*)&h2[2 * (size_t)i];
    float iv = dinv[i];
    float sqn = sqd[i];
    float a = 0.f, b = 0.f;
    for (int p = beg; p < end; p += 8) {
        int q[8]; float2 v[8]; float sq[8];
#pragma unroll
        for (int t = 0; t < 8; ++t) { int e = p + t; q[t] = csrc[e < end ? e : 0]; }
#pragma unroll
        for (int t = 0; t < 8; ++t) v[t] = *(const float2*)&h2[2 * (size_t)q[t]];
#pragma unroll
        for (int t = 0; t < 8; ++t) sq[t] = sqd[q[t]];
#pragma unroll
        for (int t = 0; t < 8; ++t) {
            float w = (p + t < end) ? sq[t] * sqn : 0.f;
            a = fmaf(v[t].x, w, a);
            b = fmaf(v[t].y, w, b);
        }
    }
    a = fmaf(hv.x, iv, a) + bias[0];
    b = fmaf(hv.y, iv, b) + bias[1];
    float m = fmaxf(a, b);
    float ls = m + logf(__expf(a - m) + __expf(b - m));
    int g = l2g[i];
    out[2 * (size_t)g + 0] = a - ls;
    out[2 * (size_t)g + 1] = b - ls;
}

// ---------------- launch ----------------

static inline dim3 g1(long long n, int tpb = 256) { return dim3((unsigned)((n + tpb - 1) / tpb)); }

extern "C" void kernel_launch(void* const* d_in, const int* in_sizes, int n_in,
                              void* d_out, int out_size, void* d_ws, size_t ws_size,
                              hipStream_t stream) {
    const float* bF   = (const float*)d_in[0];
    const float* cF   = (const float*)d_in[1];
    const float* W_c1 = (const float*)d_in[2];
    const float* b_c1 = (const float*)d_in[3];
    const float* W_c2 = (const float*)d_in[4];
    const float* b_c2 = (const float*)d_in[5];
    const float* W_at = (const float*)d_in[6];
    const float* b_at = (const float*)d_in[7];
    const float* W_b1 = (const float*)d_in[8];
    const float* b_b1 = (const float*)d_in[9];
    const float* W_b2 = (const float*)d_in[10];
    const float* b_b2 = (const float*)d_in[11];
    const float* W_b3 = (const float*)d_in[12];
    const float* b_b3 = (const float*)d_in[13];
    const int* b_src = (const int*)d_in[14];
    const int* b_dst = (const int*)d_in[15];
    const int* c_src = (const int*)d_in[16];
    const int* c_dst = (const int*)d_in[17];
    const int* map   = (const int*)d_in[18];
    const int* l2g   = (const int*)d_in[19];
    float* out = (float*)d_out;

    char* p = (char*)d_ws;
    auto alloc = [&](size_t bytes) { char* q = p; p += (bytes + 15) & ~(size_t)15; return q; };
    int*   cnt_b    = (int*)  alloc(N_BUILD * 4);
    int*   rowptr_b = (int*)  alloc((N_BUILD + 4) * 4);
    int*   cursor_b = (int*)  alloc(N_BUILD * 4);
    int*   bsum_b   = (int*)  alloc(256 * 4);
    int*   cnt_c    = (int*)  alloc(N_COMM * 4);
    int*   rowptr_c = (int*)  alloc((N_COMM + 4) * 4);
    int*   cursor_c = (int*)  alloc(N_COMM * 4);
    int*   bsum_c   = (int*)  alloc(256 * 4);
    int*   csrc_b   = (int*)  alloc((size_t)E_BUILD * 4);
    int*   csrc_c   = (int*)  alloc((size_t)E_COMM * 4);
    float* dinv_b   = (float*)alloc(N_BUILD * 4);
    float* sqd_b    = (float*)alloc(N_BUILD * 4);
    float* dinv_c   = (float*)alloc(N_COMM * 4);
    float* sqd_c    = (float*)alloc(N_COMM * 4);
    unsigned short* cFb    = (unsigned short*)alloc((size_t)N_COMM * 32 * 2);
    unsigned short* Wt_c1  = (unsigned short*)alloc(64 * 32 * 2);
    unsigned short* Wt_c2  = (unsigned short*)alloc(64 * 64 * 2);
    unsigned short* Wt_b1  = (unsigned short*)alloc(128 * 128 * 2);
    unsigned short* Wt_b2  = (unsigned short*)alloc(64 * 128 * 2);
    unsigned short* ch_bf  = (unsigned short*)alloc((size_t)N_COMM * 64 * 2);
    unsigned short* cx1_bf = (unsigned short*)alloc((size_t)N_COMM * 64 * 2);
    unsigned short* cx2_bf = (unsigned short*)alloc((size_t)N_COMM * 64 * 2);
    unsigned short* A_bf   = (unsigned short*)alloc((size_t)N_BUILD * 128 * 2); // h2
    unsigned short* B_bf   = (unsigned short*)alloc((size_t)N_BUILD * 128 * 2); // h1
    float* Dh = (float*)alloc((size_t)N_BUILD * 2 * 4);

    // ---- init (counts zero + out prefill + weight prep), then CSR build both graphs ----
    init_k<<<g1(INIT_TOT), 256, 0, stream>>>(cnt_b, cnt_c, out,
                                             cF, cFb, W_c1, Wt_c1, W_c2, Wt_c2, W_b1, Wt_b1, W_b2, Wt_b2);
    hist2_k<<<g1(E_BUILD + E_COMM), 256, 0, stream>>>(cnt_b, b_dst, cnt_c, c_dst);
    scan1m_k<<<NB_B + NB_C, 256, 0, stream>>>(cnt_b, rowptr_b, bsum_b, cnt_c, rowptr_c, bsum_c);
    scan2m_k<<<2, 256, 0, stream>>>(bsum_b, bsum_c);
    finalizem_k<<<g1(N_BUILD + N_COMM), 256, 0, stream>>>(cnt_b, rowptr_b, bsum_b, cursor_b, dinv_b, sqd_b,
                                                          cnt_c, rowptr_c, bsum_c, cursor_c, dinv_c, sqd_c);
    csr_scatterp_k<<<8 * (CB_B + CB_C), 256, 0, stream>>>(b_src, b_dst, cursor_b, csrc_b,
                                                          c_src, c_dst, cursor_c, csrc_c);

    // ---- community GCN layer 1 (32 -> 64) + relu ----
    gemm_mfma_k<32, 64, true><<<dim3((N_COMM + 63) / 64), 256, 0, stream>>>(cFb, Wt_c1, ch_bf, N_COMM);
    gatherF_k<64, true><<<g1((long long)(N_COMM / 8) * 64), 256, 0, stream>>>(rowptr_c, csrc_c, sqd_c, ch_bf, dinv_c, b_c1, cx1_bf, N_COMM / 8);

    // ---- community GCN layer 2 (64 -> 64) + relu ----
    gemm_mfma_k<64, 64, true><<<dim3((N_COMM + 63) / 64), 256, 0, stream>>>(cx1_bf, Wt_c2, ch_bf, N_COMM);
    gatherF_k<64, true><<<g1((long long)(N_COMM / 8) * 64), 256, 0, stream>>>(rowptr_c, csrc_c, sqd_c, ch_bf, dinv_c, b_c2, cx2_bf, N_COMM / 8);

    // ---- building layer 1 GEMM (fused attention), writes h1 ----
    gemm_att_k<<<dim3(N_BUILD / 64), 256, 0, stream>>>(bF, cx2_bf, map, l2g, W_at, b_at, Wt_b1, B_bf);

    // ---- fused: layer-1 aggregation + relu + layer-2 GEMM -> h2 (A_bf) ----
    gather_gemm_k<<<dim3(N_BUILD / 64), 256, 0, stream>>>(rowptr_b, csrc_b, sqd_b, B_bf, dinv_b, b_b1, Wt_b2, A_bf);

    // ---- building layer 2 aggregation + relu, fused with layer-3 XW -> Dh ----
    gather64_dot_k<<<g1((long long)(N_BUILD / 8) * 64), 256, 0, stream>>>(rowptr_b, csrc_b, sqd_b, A_bf, dinv_b, b_b2, W_b3, Dh, N_BUILD / 8);

    // ---- building layer 3 aggregation + log-softmax + scatter ----
    gather2_logsm_k<<<g1(N_BUILD), 256, 0, stream>>>(rowptr_b, csrc_b, sqd_b, Dh, dinv_b, b_b3, l2g, out, N_BUILD);
}

// Round 15
// 322.356 us; speedup vs baseline: 1.2563x; 1.0459x over previous
//
#include <hip/hip_runtime.h>
#include <hip/hip_bf16.h>
#include <math.h>

#define N_BUILD 200000
#define N_COMM  10000
#define E_BUILD 1200000
#define E_COMM  160000
#define NB_B 196   // scan blocks for building (200000/1024 rounded up)
#define NB_C 10
#define CHUNK 2048
#define CB_B ((E_BUILD + CHUNK - 1) / CHUNK)   // 586
#define CB_C ((E_COMM  + CHUNK - 1) / CHUNK)   // 79

typedef __bf16 bf16x8 __attribute__((ext_vector_type(8)));
typedef float  f32x4  __attribute__((ext_vector_type(4)));

// ---------------- bf16 helpers (RNE) ----------------
__device__ __forceinline__ unsigned short f2b(float f) {
    unsigned int u = __builtin_bit_cast(unsigned int, f);
    u += 0x7fffu + ((u >> 16) & 1u);
    return (unsigned short)(u >> 16);
}
__device__ __forceinline__ float b2f(unsigned short h) {
    unsigned int u = ((unsigned int)h) << 16;
    return __builtin_bit_cast(float, u);
}
__device__ __forceinline__ unsigned int pk2(float a, float b) {
    return (unsigned int)f2b(a) | ((unsigned int)f2b(b) << 16);
}
__device__ __forceinline__ void up8(uint4 v, float* r) {
    r[0] = b2f((unsigned short)v.x); r[1] = b2f((unsigned short)(v.x >> 16));
    r[2] = b2f((unsigned short)v.y); r[3] = b2f((unsigned short)(v.y >> 16));
    r[4] = b2f((unsigned short)v.z); r[5] = b2f((unsigned short)(v.z >> 16));
    r[6] = b2f((unsigned short)v.w); r[7] = b2f((unsigned short)(v.w >> 16));
}

// ---------------- merged init: zero counts + out prefill + all weight prep ----------------
#define INIT_TOT (N_BUILD + N_COMM + 2 * N_BUILD + N_COMM * 32 + 2048 + 4096 + 16384 + 8192)
__global__ __launch_bounds__(256) void init_k(int* cnt_b, int* cnt_c, float* out,
                                              const float* __restrict__ cF, unsigned short* __restrict__ cFb,
                                              const float* __restrict__ W_c1, unsigned short* __restrict__ Wt_c1,
                                              const float* __restrict__ W_c2, unsigned short* __restrict__ Wt_c2,
                                              const float* __restrict__ W_b1, unsigned short* __restrict__ Wt_b1,
                                              const float* __restrict__ W_b2, unsigned short* __restrict__ Wt_b2) {
    int i = blockIdx.x * blockDim.x + threadIdx.x;
    if (i < N_BUILD) { cnt_b[i] = 0; return; }
    i -= N_BUILD;
    if (i < N_COMM) { cnt_c[i] = 0; return; }
    i -= N_COMM;
    if (i < 2 * N_BUILD) { out[i] = -0.69314718056f; return; }
    i -= 2 * N_BUILD;
    if (i < N_COMM * 32) { cFb[i] = f2b(cF[i]); return; }
    i -= N_COMM * 32;
    if (i < 2048) { Wt_c1[(i % 64) * 32 + i / 64] = f2b(W_c1[i]); return; }
    i -= 2048;
    if (i < 4096) { Wt_c2[(i % 64) * 64 + i / 64] = f2b(W_c2[i]); return; }
    i -= 4096;
    if (i < 16384) { Wt_b1[(i % 128) * 128 + i / 128] = f2b(W_b1[i]); return; }
    i -= 16384;
    if (i < 8192) { Wt_b2[(i % 64) * 128 + i / 64] = f2b(W_b2[i]); }
}

// ---------------- merged CSR build kernels ----------------

__global__ __launch_bounds__(256) void hist2_k(int* cnt_b, const int* __restrict__ b_dst,
                                               int* cnt_c, const int* __restrict__ c_dst) {
    int i = blockIdx.x * blockDim.x + threadIdx.x;
    if (i < E_BUILD) atomicAdd(&cnt_b[b_dst[i]], 1);
    else if (i < E_BUILD + E_COMM) atomicAdd(&cnt_c[c_dst[i - E_BUILD]], 1);
}

__global__ __launch_bounds__(256) void scan1m_k(const int* __restrict__ cnt_b, int* __restrict__ ex_b, int* __restrict__ bs_b,
                                                const int* __restrict__ cnt_c, int* __restrict__ ex_c, int* __restrict__ bs_c) {
    __shared__ int sdata[256];
    const int tid = threadIdx.x;
    const int* cnt; int* ex; int* bs; int n, blk;
    if ((int)blockIdx.x < NB_B) { cnt = cnt_b; ex = ex_b; bs = bs_b; n = N_BUILD; blk = blockIdx.x; }
    else                        { cnt = cnt_c; ex = ex_c; bs = bs_c; n = N_COMM;  blk = blockIdx.x - NB_B; }
    const int base = blk * 1024 + tid * 4;
    int v[4]; int s = 0;
#pragma unroll
    for (int j = 0; j < 4; ++j) { v[j] = (base + j < n) ? cnt[base + j] : 0; s += v[j]; }
    sdata[tid] = s; __syncthreads();
    for (int off = 1; off < 256; off <<= 1) {
        int t = (tid >= off) ? sdata[tid - off] : 0;
        __syncthreads();
        sdata[tid] += t;
        __syncthreads();
    }
    if (tid == 255) bs[blk] = sdata[255];
    int run = sdata[tid] - s;
#pragma unroll
    for (int j = 0; j < 4; ++j) { if (base + j < n) ex[base + j] = run; run += v[j]; }
}

__global__ __launch_bounds__(256) void scan2m_k(int* bs_b, int* bs_c) {
    __shared__ int sdata[256];
    int* bs = (blockIdx.x == 0) ? bs_b : bs_c;
    int nb  = (blockIdx.x == 0) ? NB_B : NB_C;
    const int tid = threadIdx.x;
    int v = (tid < nb) ? bs[tid] : 0;
    sdata[tid] = v; __syncthreads();
    for (int off = 1; off < 256; off <<= 1) {
        int t = (tid >= off) ? sdata[tid - off] : 0;
        __syncthreads();
        sdata[tid] += t;
        __syncthreads();
    }
    if (tid < nb) bs[tid] = sdata[tid] - v;
}

__global__ __launch_bounds__(256) void finalizem_k(const int* __restrict__ cnt_b, int* rp_b, const int* __restrict__ bo_b,
                                                   int* cur_b, float* di_b,
                                                   const int* __restrict__ cnt_c, int* rp_c, const int* __restrict__ bo_c,
                                                   int* cur_c, float* di_c) {
    int i = blockIdx.x * blockDim.x + threadIdx.x;
    if (i < N_BUILD) {
        int cc = cnt_b[i];
        int r = rp_b[i] + bo_b[i >> 10];
        rp_b[i] = r; cur_b[i] = r; di_b[i] = 1.0f / (float)(cc + 1);
        if (i == 0) { rp_b[N_BUILD] = E_BUILD; rp_c[N_COMM] = E_COMM; }
    } else if (i < N_BUILD + N_COMM) {
        int ic = i - N_BUILD;
        int cc = cnt_c[ic];
        int r = rp_c[ic] + bo_c[ic >> 10];
        rp_c[ic] = r; cur_c[ic] = r; di_c[ic] = 1.0f / (float)(cc + 1);
    }
}

// XCD-range-partitioned CSR scatter (kills partial-dirty-line write amplification).
template<int NDIV>
__device__ __forceinline__ void scatter_part(const int* __restrict__ src, const int* __restrict__ dst,
                                             int* cur, const float* __restrict__ di,
                                             int2* __restrict__ cse, int E, int cid, int x) {
    int base = cid * CHUNK + threadIdx.x;
#pragma unroll
    for (int j = 0; j < CHUNK / 256; ++j, base += 256) {
        if (base < E) {
            int d = dst[base];
            if ((unsigned)d / (unsigned)NDIV == (unsigned)x) {
                int s = src[base];
                int pos = atomicAdd(&cur[d], 1);
                cse[pos] = make_int2(s, __float_as_int(sqrtf(di[s] * di[d])));
            }
        }
    }
}

__global__ __launch_bounds__(256) void csr_scatterp_k(const int* __restrict__ b_src, const int* __restrict__ b_dst,
                                                      int* cur_b, const float* __restrict__ di_b, int2* __restrict__ cse_b,
                                                      const int* __restrict__ c_src, const int* __restrict__ c_dst,
                                                      int* cur_c, const float* __restrict__ di_c, int2* __restrict__ cse_c) {
    int bid = blockIdx.x;
    if (bid < 8 * CB_B) {
        scatter_part<N_BUILD / 8>(b_src, b_dst, cur_b, di_b, cse_b, E_BUILD, bid >> 3, bid & 7);
    } else {
        bid -= 8 * CB_B;
        scatter_part<N_COMM / 8>(c_src, c_dst, cur_c, di_c, cse_c, E_COMM, bid >> 3, bid & 7);
    }
}

// ---------------- MFMA GEMM: H[M][N] (bf16) = X[M][K] (bf16) @ Wt[N][K]^T ----------------
template<int K, int N, bool GUARD>
__global__ __launch_bounds__(256) void gemm_mfma_k(const unsigned short* __restrict__ X,
                                                   const unsigned short* __restrict__ Wt,
                                                   unsigned short* __restrict__ H, int M) {
    constexpr int GPR = K / 8;
    __shared__ unsigned short sA[64 * K];
    __shared__ unsigned short sB[N * K];
    const int tid  = threadIdx.x;
    const int row0 = blockIdx.x * 64;

    for (int idx = tid; idx < 64 * GPR; idx += 256) {
        int r = idx / GPR, g = idx % GPR;
        uint4 v = make_uint4(0u, 0u, 0u, 0u);
        if (!GUARD || row0 + r < M)
            v = *(const uint4*)&X[(size_t)(row0 + r) * K + g * 8];
        int gs = g ^ (r & (GPR - 1));
        *(uint4*)&sA[r * K + gs * 8] = v;
    }
    for (int idx = tid; idx < N * GPR; idx += 256) {
        int r = idx / GPR, g = idx % GPR;
        uint4 v = *(const uint4*)&Wt[(size_t)r * K + g * 8];
        int gs = g ^ (r & (GPR - 1));
        *(uint4*)&sB[r * K + gs * 8] = v;
    }
    __syncthreads();

    const int wave = tid >> 6, lane = tid & 63;
    const int rA = wave * 16 + (lane & 15);
    const int kg = lane >> 4;

    f32x4 zero = {0.f, 0.f, 0.f, 0.f};
    f32x4 acc[N / 16];
#pragma unroll
    for (int t = 0; t < N / 16; ++t) acc[t] = zero;

#pragma unroll
    for (int ks = 0; ks < K / 32; ++ks) {
        int gA = (ks * 4 + kg) ^ (rA & (GPR - 1));
        bf16x8 a = *(const bf16x8*)&sA[rA * K + gA * 8];
#pragma unroll
        for (int t = 0; t < N / 16; ++t) {
            int rB = t * 16 + (lane & 15);
            int gB = (ks * 4 + kg) ^ (rB & (GPR - 1));
            bf16x8 b = *(const bf16x8*)&sB[rB * K + gB * 8];
            acc[t] = __builtin_amdgcn_mfma_f32_16x16x32_bf16(a, b, acc[t], 0, 0, 0);
        }
    }

    const int crow = wave * 16 + (lane >> 4) * 4;
    const int ccol = lane & 15;
#pragma unroll
    for (int t = 0; t < N / 16; ++t) {
#pragma unroll
        for (int j = 0; j < 4; ++j) {
            int r = row0 + crow + j;
            if (!GUARD || r < M)
                H[(size_t)r * N + t * 16 + ccol] = f2b(acc[t][j]);
        }
    }
}

// ---------------- fused attention + building GEMM layer 1 (K=N=128) ----------------
__global__ __launch_bounds__(256) void gemm_att_k(const float* __restrict__ bF,
                                                  const unsigned short* __restrict__ cx,
                                                  const int* __restrict__ map,
                                                  const int* __restrict__ l2g,
                                                  const float* __restrict__ Watt,  // [128][2]
                                                  const float* __restrict__ batt,  // [2]
                                                  const unsigned short* __restrict__ Wt,  // [128][128]
                                                  unsigned short* __restrict__ H) {
    constexpr int K = 128, N = 128, GPR = 16;
    __shared__ unsigned short sA[64 * K];
    __shared__ unsigned short sB[N * K];
    __shared__ float sWt[256];
    const int tid = threadIdx.x;
    const int row0 = blockIdx.x * 64;
    sWt[tid] = Watt[tid];
    for (int idx = tid; idx < N * GPR; idx += 256) {
        int r = idx / GPR, g = idx % GPR;
        uint4 v = *(const uint4*)&Wt[(size_t)r * K + g * 8];
        int gs = g ^ (r & (GPR - 1));
        *(uint4*)&sB[r * K + gs * 8] = v;
    }
    __syncthreads();
    {
        const int r = tid >> 2, j = tid & 3;   // N_BUILD % 64 == 0 -> no guard
        const int g = l2g[row0 + r];
        float vals[32];
        if (j < 2) {
            const float* f1 = &bF[(size_t)g * 64 + j * 32];
#pragma unroll
            for (int t = 0; t < 8; ++t) {
                float4 v = *(const float4*)&f1[t * 4];
                vals[t*4+0]=v.x; vals[t*4+1]=v.y; vals[t*4+2]=v.z; vals[t*4+3]=v.w;
            }
        } else {
            const unsigned short* f2 = &cx[(size_t)map[g] * 64 + (j & 1) * 32];
#pragma unroll
            for (int t = 0; t < 4; ++t) {
                uint4 u = *(const uint4*)&f2[t * 8];
                up8(u, &vals[t * 8]);
            }
        }
        float l0 = 0.f, l1 = 0.f;
        const int ch0 = j * 32;
#pragma unroll
        for (int t = 0; t < 32; ++t) {
            l0 = fmaf(vals[t], sWt[(ch0 + t) * 2 + 0], l0);
            l1 = fmaf(vals[t], sWt[(ch0 + t) * 2 + 1], l1);
        }
        l0 += __shfl_xor(l0, 1, 4); l0 += __shfl_xor(l0, 2, 4);
        l1 += __shfl_xor(l1, 1, 4); l1 += __shfl_xor(l1, 2, 4);
        l0 += batt[0]; l1 += batt[1];
        float mm = fmaxf(l0, l1);
        float e0 = __expf(l0 - mm), e1 = __expf(l1 - mm);
        float a = ((j < 2) ? e0 : e1) / (e0 + e1);
#pragma unroll
        for (int t = 0; t < 4; ++t) {
            uint4 o;
            o.x = pk2(vals[t*8+0]*a, vals[t*8+1]*a);
            o.y = pk2(vals[t*8+2]*a, vals[t*8+3]*a);
            o.z = pk2(vals[t*8+4]*a, vals[t*8+5]*a);
            o.w = pk2(vals[t*8+6]*a, vals[t*8+7]*a);
            int gi = j * 4 + t;
            int gs = gi ^ (r & (GPR - 1));
            *(uint4*)&sA[r * K + gs * 8] = o;
        }
    }
    __syncthreads();
    const int wave = tid >> 6, lane = tid & 63;
    const int rA = wave * 16 + (lane & 15);
    const int kg = lane >> 4;
    f32x4 zero = {0.f, 0.f, 0.f, 0.f};
    f32x4 acc[8];
#pragma unroll
    for (int t = 0; t < 8; ++t) acc[t] = zero;
#pragma unroll
    for (int ks = 0; ks < 4; ++ks) {
        int gA = (ks * 4 + kg) ^ (rA & 15);
        bf16x8 a = *(const bf16x8*)&sA[rA * K + gA * 8];
#pragma unroll
        for (int t = 0; t < 8; ++t) {
            int rB = t * 16 + (lane & 15);
            int gB = (ks * 4 + kg) ^ (rB & 15);
            bf16x8 b = *(const bf16x8*)&sB[rB * K + gB * 8];
            acc[t] = __builtin_amdgcn_mfma_f32_16x16x32_bf16(a, b, acc[t], 0, 0, 0);
        }
    }
    const int crow = wave * 16 + (lane >> 4) * 4;
    const int ccol = lane & 15;
#pragma unroll
    for (int t = 0; t < 8; ++t)
#pragma unroll
        for (int jj = 0; jj < 4; ++jj)
            H[(size_t)(row0 + crow + jj) * N + t * 16 + ccol] = f2b(acc[t][jj]);
}

// ---------------- fused building layer-1 aggregation + layer-2 GEMM ----------------
// Block handles 64 nodes: (1) gather-aggregate o1 = relu(agg(h1)+h1/deg+b1) straight
// into LDS (never touches global), (2) MFMA o1 @ Wt_b2 -> h2[64][64].
__global__ __launch_bounds__(256) void gather_gemm_k(const int* __restrict__ rowptr,
                                                     const int2* __restrict__ cse,
                                                     const unsigned short* __restrict__ h,     // h1 [N][128]
                                                     const float* __restrict__ dinv,
                                                     const float* __restrict__ bias,           // b_b1 [128]
                                                     const unsigned short* __restrict__ Wt,    // Wt_b2 [64][128]
                                                     unsigned short* __restrict__ H) {         // h2 [N][64]
    constexpr int K = 128, N = 64, GPR = 16;
    __shared__ unsigned short sA[64 * K];
    __shared__ unsigned short sB[N * K];
    const int tid = threadIdx.x;
    const int row0 = blockIdx.x * 64;
    // stage Wt_b2 (swizzled)
    for (int idx = tid; idx < N * GPR; idx += 256) {
        int r = idx / GPR, g = idx % GPR;
        uint4 v = *(const uint4*)&Wt[(size_t)r * K + g * 8];
        int gs = g ^ (r & (GPR - 1));
        *(uint4*)&sB[r * K + gs * 8] = v;
    }
    // gather phase: each wave aggregates 16 nodes (4 sub-batches of 4 nodes, 16 lanes/node)
    const int lane = tid & 63;
    const int wave = tid >> 6;
    const int slot = lane >> 4;          // node slot within sub-batch
    const int c = (lane & 15) * 8;       // channel base (8 ch = 16B per lane)
#pragma unroll
    for (int sb = 0; sb < 4; ++sb) {
        const int r = wave * 16 + sb * 4 + slot;   // LDS row 0..63
        const int node = row0 + r;
        int beg = rowptr[node], end = rowptr[node + 1];
        uint4 hv = *(const uint4*)&h[(size_t)node * K + c];
        float iv = dinv[node];
        float4 bb0 = *(const float4*)&bias[c];
        float4 bb1 = *(const float4*)&bias[c + 4];
        float acc[8];
#pragma unroll
        for (int i = 0; i < 8; ++i) acc[i] = 0.f;
        for (int p = beg; p < end; p += 8) {
            int2 q[8]; uint4 v[8];
#pragma unroll
            for (int t = 0; t < 8; ++t) { int e = p + t; q[t] = cse[e < end ? e : 0]; }
#pragma unroll
            for (int t = 0; t < 8; ++t) v[t] = *(const uint4*)&h[(size_t)q[t].x * K + c];
#pragma unroll
            for (int t = 0; t < 8; ++t) {
                float w = (p + t < end) ? __int_as_float(q[t].y) : 0.f;
                float rr[8]; up8(v[t], rr);
#pragma unroll
                for (int i = 0; i < 8; ++i) acc[i] = fmaf(rr[i], w, acc[i]);
            }
        }
        float hr[8]; up8(hv, hr);
        float o[8];
        o[0] = fmaf(hr[0], iv, acc[0]) + bb0.x; o[1] = fmaf(hr[1], iv, acc[1]) + bb0.y;
        o[2] = fmaf(hr[2], iv, acc[2]) + bb0.z; o[3] = fmaf(hr[3], iv, acc[3]) + bb0.w;
        o[4] = fmaf(hr[4], iv, acc[4]) + bb1.x; o[5] = fmaf(hr[5], iv, acc[5]) + bb1.y;
        o[6] = fmaf(hr[6], iv, acc[6]) + bb1.z; o[7] = fmaf(hr[7], iv, acc[7]) + bb1.w;
#pragma unroll
        for (int i = 0; i < 8; ++i) o[i] = fmaxf(o[i], 0.f);
        uint4 ov;
        ov.x = pk2(o[0], o[1]); ov.y = pk2(o[2], o[3]);
        ov.z = pk2(o[4], o[5]); ov.w = pk2(o[6], o[7]);
        const int g = lane & 15;
        const int gs = g ^ (r & (GPR - 1));
        *(uint4*)&sA[r * K + gs * 8] = ov;
    }
    __syncthreads();
    // MFMA phase: h2[64][64] = sA @ sB^T
    const int rA = wave * 16 + (lane & 15);
    const int kg = lane >> 4;
    f32x4 zero = {0.f, 0.f, 0.f, 0.f};
    f32x4 acc[4];
#pragma unroll
    for (int t = 0; t < 4; ++t) acc[t] = zero;
#pragma unroll
    for (int ks = 0; ks < 4; ++ks) {
        int gA = (ks * 4 + kg) ^ (rA & (GPR - 1));
        bf16x8 a = *(const bf16x8*)&sA[rA * K + gA * 8];
#pragma unroll
        for (int t = 0; t < 4; ++t) {
            int rB = t * 16 + (lane & 15);
            int gB = (ks * 4 + kg) ^ (rB & (GPR - 1));
            bf16x8 b = *(const bf16x8*)&sB[rB * K + gB * 8];
            acc[t] = __builtin_amdgcn_mfma_f32_16x16x32_bf16(a, b, acc[t], 0, 0, 0);
        }
    }
    const int crow = wave * 16 + (lane >> 4) * 4;
    const int ccol = lane & 15;
#pragma unroll
    for (int t = 0; t < 4; ++t)
#pragma unroll
        for (int jj = 0; jj < 4; ++jj)
            H[(size_t)(row0 + crow + jj) * 64 + t * 16 + ccol] = f2b(acc[t][jj]);
}

// ---------------- gathers: deep lane-split node packing ----------------
template<int F, bool RELU>
__global__ __launch_bounds__(256) void gatherF_k(const int* __restrict__ rowptr,
                                                 const int2* __restrict__ cse,
                                                 const unsigned short* __restrict__ h,
                                                 const float* __restrict__ dinv,
                                                 const float* __restrict__ bias,
                                                 unsigned short* __restrict__ out, int nGrp) {
    constexpr int LPN = F / 8;
    constexpr int NPW = 64 / LPN;
    int wid = (blockIdx.x * blockDim.x + threadIdx.x) >> 6;
    int lane = threadIdx.x & 63;
    if (wid >= nGrp) return;
    int node = wid * NPW + lane / LPN;
    int c = (lane % LPN) * 8;
    int beg = rowptr[node], end = rowptr[node + 1];
    uint4 hv = *(const uint4*)&h[(size_t)node * F + c];
    float iv = dinv[node];
    float4 bb0 = *(const float4*)&bias[c];
    float4 bb1 = *(const float4*)&bias[c + 4];
    float acc[8];
#pragma unroll
    for (int i = 0; i < 8; ++i) acc[i] = 0.f;
    for (int p = beg; p < end; p += 8) {
        int2 q[8]; uint4 v[8];
#pragma unroll
        for (int t = 0; t < 8; ++t) { int e = p + t; q[t] = cse[e < end ? e : 0]; }
#pragma unroll
        for (int t = 0; t < 8; ++t) v[t] = *(const uint4*)&h[(size_t)q[t].x * F + c];
#pragma unroll
        for (int t = 0; t < 8; ++t) {
            float w = (p + t < end) ? __int_as_float(q[t].y) : 0.f;
            float r[8]; up8(v[t], r);
#pragma unroll
            for (int i = 0; i < 8; ++i) acc[i] = fmaf(r[i], w, acc[i]);
        }
    }
    float hr[8]; up8(hv, hr);
    float o[8];
    o[0] = fmaf(hr[0], iv, acc[0]) + bb0.x; o[1] = fmaf(hr[1], iv, acc[1]) + bb0.y;
    o[2] = fmaf(hr[2], iv, acc[2]) + bb0.z; o[3] = fmaf(hr[3], iv, acc[3]) + bb0.w;
    o[4] = fmaf(hr[4], iv, acc[4]) + bb1.x; o[5] = fmaf(hr[5], iv, acc[5]) + bb1.y;
    o[6] = fmaf(hr[6], iv, acc[6]) + bb1.z; o[7] = fmaf(hr[7], iv, acc[7]) + bb1.w;
    if (RELU) {
#pragma unroll
        for (int i = 0; i < 8; ++i) o[i] = fmaxf(o[i], 0.f);
    }
    uint4 ov;
    ov.x = pk2(o[0], o[1]); ov.y = pk2(o[2], o[3]);
    ov.z = pk2(o[4], o[5]); ov.w = pk2(o[6], o[7]);
    *(uint4*)&out[(size_t)node * F + c] = ov;
}

// building layer-2 gather fused with layer-3 XW (64 -> 2): 8 nodes/wave, 8 lanes/node.
__global__ __launch_bounds__(256) void gather64_dot_k(const int* __restrict__ rowptr,
                                                      const int2* __restrict__ cse,
                                                      const unsigned short* __restrict__ h,
                                                      const float* __restrict__ dinv,
                                                      const float* __restrict__ bias,
                                                      const float* __restrict__ W3,  // [64][2]
                                                      float* __restrict__ Dh, int nOct) {
    int wid = (blockIdx.x * blockDim.x + threadIdx.x) >> 6;
    int lane = threadIdx.x & 63;
    if (wid >= nOct) return;
    int node = wid * 8 + (lane >> 3);
    int sl = lane & 7, c = sl * 8;
    int beg = rowptr[node], end = rowptr[node + 1];
    uint4 hv = *(const uint4*)&h[(size_t)node * 64 + c];
    float iv = dinv[node];
    float4 bb0 = *(const float4*)&bias[c];
    float4 bb1 = *(const float4*)&bias[c + 4];
    float4 w4[4];
#pragma unroll
    for (int i = 0; i < 4; ++i) w4[i] = *(const float4*)&W3[c * 2 + i * 4];
    float acc[8];
#pragma unroll
    for (int i = 0; i < 8; ++i) acc[i] = 0.f;
    for (int p = beg; p < end; p += 8) {
        int2 q[8]; uint4 v[8];
#pragma unroll
        for (int t = 0; t < 8; ++t) { int e = p + t; q[t] = cse[e < end ? e : 0]; }
#pragma unroll
        for (int t = 0; t < 8; ++t) v[t] = *(const uint4*)&h[(size_t)q[t].x * 64 + c];
#pragma unroll
        for (int t = 0; t < 8; ++t) {
            float w = (p + t < end) ? __int_as_float(q[t].y) : 0.f;
            float r[8]; up8(v[t], r);
#pragma unroll
            for (int i = 0; i < 8; ++i) acc[i] = fmaf(r[i], w, acc[i]);
        }
    }
    float hr[8]; up8(hv, hr);
    float o[8];
    o[0] = fmaf(hr[0], iv, acc[0]) + bb0.x; o[1] = fmaf(hr[1], iv, acc[1]) + bb0.y;
    o[2] = fmaf(hr[2], iv, acc[2]) + bb0.z; o[3] = fmaf(hr[3], iv, acc[3]) + bb0.w;
    o[4] = fmaf(hr[4], iv, acc[4]) + bb1.x; o[5] = fmaf(hr[5], iv, acc[5]) + bb1.y;
    o[6] = fmaf(hr[6], iv, acc[6]) + bb1.z; o[7] = fmaf(hr[7], iv, acc[7]) + bb1.w;
#pragma unroll
    for (int i = 0; i < 8; ++i) o[i] = fmaxf(o[i], 0.f);
    float d0 = 0.f, d1 = 0.f;
#pragma unroll
    for (int i = 0; i < 4; ++i) {
        d0 = fmaf(o[2*i],   w4[i].x, d0); d0 = fmaf(o[2*i+1], w4[i].z, d0);
        d1 = fmaf(o[2*i],   w4[i].y, d1); d1 = fmaf(o[2*i+1], w4[i].w, d1);
    }
#pragma unroll
    for (int m = 1; m < 8; m <<= 1) {
        d0 += __shfl_xor(d0, m, 8);
        d1 += __shfl_xor(d1, m, 8);
    }
    if (sl == 0) {
        Dh[2 * (size_t)node + 0] = d0;
        Dh[2 * (size_t)node + 1] = d1;
    }
}

// final layer: gather (F=2, f32) + bias + log-softmax + scatter to global order
__global__ __launch_bounds__(256) void gather2_logsm_k(const int* __restrict__ rowptr,
                                                       const int2* __restrict__ cse,
                                                       const float* __restrict__ h2,
                                                       const float* __restrict__ dinv,
                                                       const float* __restrict__ bias,
                                                       const int* __restrict__ l2g,
                                                       float* __restrict__ out, int n) {
    int i = blockIdx.x * blockDim.x + threadIdx.x;
    if (i >= n) return;
    int beg = rowptr[i], end = rowptr[i + 1];
    float2 hv = *(const float2*)&h2[2 * (size_t)i];
    float iv = dinv[i];
    float a = 0.f, b = 0.f;
    for (int p = beg; p < end; p += 8) {
        int2 q[8]; float2 v[8];
#pragma unroll
        for (int t = 0; t < 8; ++t) { int e = p + t; q[t] = cse[e < end ? e : 0]; }
#pragma unroll
        for (int t = 0; t < 8; ++t) v[t] = *(const float2*)&h2[2 * (size_t)q[t].x];
#pragma unroll
        for (int t = 0; t < 8; ++t) {
            float w = (p + t < end) ? __int_as_float(q[t].y) : 0.f;
            a = fmaf(v[t].x, w, a);
            b = fmaf(v[t].y, w, b);
        }
    }
    a = fmaf(hv.x, iv, a) + bias[0];
    b = fmaf(hv.y, iv, b) + bias[1];
    float m = fmaxf(a, b);
    float ls = m + logf(__expf(a - m) + __expf(b - m));
    int g = l2g[i];
    out[2 * (size_t)g + 0] = a - ls;
    out[2 * (size_t)g + 1] = b - ls;
}

// ---------------- launch ----------------

static inline dim3 g1(long long n, int tpb = 256) { return dim3((unsigned)((n + tpb - 1) / tpb)); }

extern "C" void kernel_launch(void* const* d_in, const int* in_sizes, int n_in,
                              void* d_out, int out_size, void* d_ws, size_t ws_size,
                              hipStream_t stream) {
    const float* bF   = (const float*)d_in[0];
    const float* cF   = (const float*)d_in[1];
    const float* W_c1 = (const float*)d_in[2];
    const float* b_c1 = (const float*)d_in[3];
    const float* W_c2 = (const float*)d_in[4];
    const float* b_c2 = (const float*)d_in[5];
    const float* W_at = (const float*)d_in[6];
    const float* b_at = (const float*)d_in[7];
    const float* W_b1 = (const float*)d_in[8];
    const float* b_b1 = (const float*)d_in[9];
    const float* W_b2 = (const float*)d_in[10];
    const float* b_b2 = (const float*)d_in[11];
    const float* W_b3 = (const float*)d_in[12];
    const float* b_b3 = (const float*)d_in[13];
    const int* b_src = (const int*)d_in[14];
    const int* b_dst = (const int*)d_in[15];
    const int* c_src = (const int*)d_in[16];
    const int* c_dst = (const int*)d_in[17];
    const int* map   = (const int*)d_in[18];
    const int* l2g   = (const int*)d_in[19];
    float* out = (float*)d_out;

    char* p = (char*)d_ws;
    auto alloc = [&](size_t bytes) { char* q = p; p += (bytes + 15) & ~(size_t)15; return q; };
    int*   cnt_b    = (int*)  alloc(N_BUILD * 4);
    int*   rowptr_b = (int*)  alloc((N_BUILD + 4) * 4);
    int*   cursor_b = (int*)  alloc(N_BUILD * 4);
    int*   bsum_b   = (int*)  alloc(256 * 4);
    int*   cnt_c    = (int*)  alloc(N_COMM * 4);
    int*   rowptr_c = (int*)  alloc((N_COMM + 4) * 4);
    int*   cursor_c = (int*)  alloc(N_COMM * 4);
    int*   bsum_c   = (int*)  alloc(256 * 4);
    int2*  cse_b    = (int2*) alloc((size_t)E_BUILD * 8);
    int2*  cse_c    = (int2*) alloc((size_t)E_COMM * 8);
    float* dinv_b   = (float*)alloc(N_BUILD * 4);
    float* dinv_c   = (float*)alloc(N_COMM * 4);
    unsigned short* cFb    = (unsigned short*)alloc((size_t)N_COMM * 32 * 2);
    unsigned short* Wt_c1  = (unsigned short*)alloc(64 * 32 * 2);
    unsigned short* Wt_c2  = (unsigned short*)alloc(64 * 64 * 2);
    unsigned short* Wt_b1  = (unsigned short*)alloc(128 * 128 * 2);
    unsigned short* Wt_b2  = (unsigned short*)alloc(64 * 128 * 2);
    unsigned short* ch_bf  = (unsigned short*)alloc((size_t)N_COMM * 64 * 2);
    unsigned short* cx1_bf = (unsigned short*)alloc((size_t)N_COMM * 64 * 2);
    unsigned short* cx2_bf = (unsigned short*)alloc((size_t)N_COMM * 64 * 2);
    unsigned short* A_bf   = (unsigned short*)alloc((size_t)N_BUILD * 128 * 2); // h2
    unsigned short* B_bf   = (unsigned short*)alloc((size_t)N_BUILD * 128 * 2); // h1
    float* Dh = (float*)alloc((size_t)N_BUILD * 2 * 4);

    // ---- init (counts zero + out prefill + weight prep), then CSR build both graphs ----
    init_k<<<g1(INIT_TOT), 256, 0, stream>>>(cnt_b, cnt_c, out,
                                             cF, cFb, W_c1, Wt_c1, W_c2, Wt_c2, W_b1, Wt_b1, W_b2, Wt_b2);
    hist2_k<<<g1(E_BUILD + E_COMM), 256, 0, stream>>>(cnt_b, b_dst, cnt_c, c_dst);
    scan1m_k<<<NB_B + NB_C, 256, 0, stream>>>(cnt_b, rowptr_b, bsum_b, cnt_c, rowptr_c, bsum_c);
    scan2m_k<<<2, 256, 0, stream>>>(bsum_b, bsum_c);
    finalizem_k<<<g1(N_BUILD + N_COMM), 256, 0, stream>>>(cnt_b, rowptr_b, bsum_b, cursor_b, dinv_b,
                                                          cnt_c, rowptr_c, bsum_c, cursor_c, dinv_c);
    csr_scatterp_k<<<8 * (CB_B + CB_C), 256, 0, stream>>>(b_src, b_dst, cursor_b, dinv_b, cse_b,
                                                          c_src, c_dst, cursor_c, dinv_c, cse_c);

    // ---- community GCN layer 1 (32 -> 64) + relu ----
    gemm_mfma_k<32, 64, true><<<dim3((N_COMM + 63) / 64), 256, 0, stream>>>(cFb, Wt_c1, ch_bf, N_COMM);
    gatherF_k<64, true><<<g1((long long)(N_COMM / 8) * 64), 256, 0, stream>>>(rowptr_c, cse_c, ch_bf, dinv_c, b_c1, cx1_bf, N_COMM / 8);

    // ---- community GCN layer 2 (64 -> 64) + relu ----
    gemm_mfma_k<64, 64, true><<<dim3((N_COMM + 63) / 64), 256, 0, stream>>>(cx1_bf, Wt_c2, ch_bf, N_COMM);
    gatherF_k<64, true><<<g1((long long)(N_COMM / 8) * 64), 256, 0, stream>>>(rowptr_c, cse_c, ch_bf, dinv_c, b_c2, cx2_bf, N_COMM / 8);

    // ---- building layer 1 GEMM (fused attention), writes h1 ----
    gemm_att_k<<<dim3(N_BUILD / 64), 256, 0, stream>>>(bF, cx2_bf, map, l2g, W_at, b_at, Wt_b1, B_bf);

    // ---- fused: layer-1 aggregation + relu + layer-2 GEMM -> h2 (A_bf) ----
    gather_gemm_k<<<dim3(N_BUILD / 64), 256, 0, stream>>>(rowptr_b, cse_b, B_bf, dinv_b, b_b1, Wt_b2, A_bf);

    // ---- building layer 2 aggregation + relu, fused with layer-3 XW -> Dh ----
    gather64_dot_k<<<g1((long long)(N_BUILD / 8) * 64), 256, 0, stream>>>(rowptr_b, cse_b, A_bf, dinv_b, b_b2, W_b3, Dh, N_BUILD / 8);

    // ---- building layer 3 aggregation + log-softmax + scatter ----
    gather2_logsm_k<<<g1(N_BUILD), 256, 0, stream>>>(rowptr_b, cse_b, Dh, dinv_b, b_b3, l2g, out, N_BUILD);
}